// Round 1
// baseline (607.374 us; speedup 1.0000x reference)
//
#include <hip/hip_runtime.h>
#include <cstdint>
#include <cstddef>

#define S_TOK 8192
#define DM    1024
#define NE    16
#define NF    4096
#define CAP   512

typedef __attribute__((ext_vector_type(8))) short bf16x8;
typedef __attribute__((ext_vector_type(4))) float f32x4;

__device__ __forceinline__ unsigned short f2bf(float f) {
  __bf16 b = (__bf16)f;
  return __builtin_bit_cast(unsigned short, b);
}
__device__ __forceinline__ unsigned pk2(float a, float b) {
  return (unsigned)f2bf(a) | ((unsigned)f2bf(b) << 16);
}
// LDS tiles are [row][64 bf16] = 128 B rows; XOR-swizzle to kill 16-way conflicts.
__device__ __forceinline__ int swz(int row, int kbyte) {
  return row * 128 + (kbyte ^ (((row >> 1) & 7) << 4));
}

// ---------------- gating: logits fp32, softmax, argmax -----------------
__global__ void __launch_bounds__(256)
gate_kernel(const float* __restrict__ X, const float* __restrict__ Wg,
            int* __restrict__ idx, float* __restrict__ gval) {
  const int tid  = threadIdx.x;
  const int lane = tid & 63;
  const int wid  = tid >> 6;
  const int e = lane & 15, q = lane >> 4;
  const int t0 = blockIdx.x * 16 + wid * 4;   // this wave's 4 tokens
  const int mbase = q * 256;

  const float* xp0 = X + (size_t)(t0 + 0) * DM + mbase;
  const float* xp1 = X + (size_t)(t0 + 1) * DM + mbase;
  const float* xp2 = X + (size_t)(t0 + 2) * DM + mbase;
  const float* xp3 = X + (size_t)(t0 + 3) * DM + mbase;
  const float* wp  = Wg + (size_t)mbase * NE + e;

  float a0 = 0.f, a1 = 0.f, a2 = 0.f, a3 = 0.f;
#pragma unroll 4
  for (int i = 0; i < 64; ++i) {
    float4 x0 = *(const float4*)(xp0 + i * 4);
    float4 x1 = *(const float4*)(xp1 + i * 4);
    float4 x2 = *(const float4*)(xp2 + i * 4);
    float4 x3 = *(const float4*)(xp3 + i * 4);
    float w0 = wp[(i * 4 + 0) * NE];
    float w1 = wp[(i * 4 + 1) * NE];
    float w2 = wp[(i * 4 + 2) * NE];
    float w3 = wp[(i * 4 + 3) * NE];
    a0 = fmaf(x0.x, w0, fmaf(x0.y, w1, fmaf(x0.z, w2, fmaf(x0.w, w3, a0))));
    a1 = fmaf(x1.x, w0, fmaf(x1.y, w1, fmaf(x1.z, w2, fmaf(x1.w, w3, a1))));
    a2 = fmaf(x2.x, w0, fmaf(x2.y, w1, fmaf(x2.z, w2, fmaf(x2.w, w3, a2))));
    a3 = fmaf(x3.x, w0, fmaf(x3.y, w1, fmaf(x3.z, w2, fmaf(x3.w, w3, a3))));
  }
  // reduce the 4 m-quarters (lanes differing in bits 4..5)
#pragma unroll
  for (int s = 16; s < 64; s <<= 1) {
    a0 += __shfl_xor(a0, s, 64);
    a1 += __shfl_xor(a1, s, 64);
    a2 += __shfl_xor(a2, s, 64);
    a3 += __shfl_xor(a3, s, 64);
  }
  // 16-lane group q handles token t0+q; lane holds logit for expert e
  float l = (q == 0) ? a0 : (q == 1) ? a1 : (q == 2) ? a2 : a3;
  float bv = l; int bi = e;
#pragma unroll
  for (int s = 1; s < 16; s <<= 1) {
    float ov = __shfl_xor(bv, s, 16);
    int   oi = __shfl_xor(bi, s, 16);
    if (ov > bv || (ov == bv && oi < bi)) { bv = ov; bi = oi; }
  }
  float p  = expf(l - bv);
  float sm = p;
#pragma unroll
  for (int s = 1; s < 16; s <<= 1) sm += __shfl_xor(sm, s, 16);
  if (e == 0) {
    idx[t0 + q]  = bi;
    gval[t0 + q] = 1.0f / sm;   // softmax value at argmax
  }
}

// ---------------- routing scan: capacity-limited slot assignment -------
__global__ void __launch_bounds__(1024)
scan_kernel(const int* __restrict__ idx, int* __restrict__ s2t) {
  const int tid = threadIdx.x;
#pragma unroll
  for (int k = 0; k < 8; ++k) s2t[tid + k * 1024] = -1;
  __shared__ int base[16];
  __shared__ int wavecnt[16][16];
  if (tid < 16) base[tid] = 0;
  __syncthreads();
  const int wid = tid >> 6, lane = tid & 63;
  const unsigned long long ltmask = (1ull << lane) - 1ull;
  for (int c = 0; c < 8; ++c) {
    const int t = c * 1024 + tid;
    const int e = idx[t];
    int rank = 0;
#pragma unroll
    for (int ee = 0; ee < 16; ++ee) {
      unsigned long long m = __ballot(e == ee);
      if (lane == 0) wavecnt[wid][ee] = __popcll(m);
      if (ee == e) rank = __popcll(m & ltmask);
    }
    __syncthreads();
    if (tid < 16) {
      int s = base[tid];
#pragma unroll
      for (int w = 0; w < 16; ++w) { int cc = wavecnt[w][tid]; wavecnt[w][tid] = s; s += cc; }
      base[tid] = s;
    }
    __syncthreads();
    const int loc = wavecnt[wid][e] + rank;
    if (loc < CAP) s2t[e * CAP + loc] = t;
    __syncthreads();
  }
}

// ---------------- GEMM1: H[e] = relu(gather(x)[e] @ w1[e]) -------------
template <int BN>
__global__ void __launch_bounds__(512)
gemm1_kernel(const float* __restrict__ X, const float* __restrict__ W1,
             const int* __restrict__ s2t, unsigned short* __restrict__ H) {
  constexpr int BM = 256, BK = 64;
  constexpr int WN = BN / 4;
  constexpr int MI = 8, NI = WN / 16;
  constexpr int KSPAN = BN / 16;      // weight k-rows per column-group
  constexpr int NJC = KSPAN / 8;
  constexpr int NT = DM / BK;

  __shared__ __align__(16) char lds[BM * 128 + BN * 128];
  char* const As = lds;
  char* const Bs = lds + BM * 128;

  const int tid = threadIdx.x;
  const int lane = tid & 63, wid = tid >> 6;
  const int wr = wid >> 2, wc = wid & 3;
  const int ln15 = lane & 15, l16 = lane >> 4;
  const int e  = blockIdx.z;
  const int m0 = blockIdx.x * BM;
  const int n0 = blockIdx.y * BN;

  const int ar  = tid >> 1;            // A row 0..255
  const int akh = (tid & 1) * 32;      // k half
  const int tok = s2t[e * CAP + m0 + ar];
  const float* const asrc = X + (size_t)(tok < 0 ? 0 : tok) * DM + akh;

  const int bn  = (tid & (BN / 2 - 1)) * 2;
  const int bkq = tid / (BN / 2);
  const float* const bsrc = W1 + (size_t)e * DM * NF + (size_t)bkq * KSPAN * NF + n0 + bn;

  f32x4 acc[MI][NI];
#pragma unroll
  for (int mi = 0; mi < MI; ++mi)
#pragma unroll
    for (int ni = 0; ni < NI; ++ni) acc[mi][ni] = f32x4{0.f, 0.f, 0.f, 0.f};

  uint4 aPk[4], bLo[NJC], bHi[NJC];

  auto LOAD = [&](int kt) {
    const int k0 = kt * BK;
    if (tok >= 0) {
#pragma unroll
      for (int j = 0; j < 4; ++j) {
        float4 v0 = *(const float4*)(asrc + k0 + j * 8);
        float4 v1 = *(const float4*)(asrc + k0 + j * 8 + 4);
        aPk[j] = make_uint4(pk2(v0.x, v0.y), pk2(v0.z, v0.w),
                            pk2(v1.x, v1.y), pk2(v1.z, v1.w));
      }
    } else {
#pragma unroll
      for (int j = 0; j < 4; ++j) aPk[j] = make_uint4(0u, 0u, 0u, 0u);
    }
    const float* bp = bsrc + (size_t)k0 * NF;
#pragma unroll
    for (int jc = 0; jc < NJC; ++jc) {
      float2 v[8];
#pragma unroll
      for (int r = 0; r < 8; ++r) v[r] = *(const float2*)(bp + (size_t)(jc * 8 + r) * NF);
      bLo[jc] = make_uint4(pk2(v[0].x, v[1].x), pk2(v[2].x, v[3].x),
                           pk2(v[4].x, v[5].x), pk2(v[6].x, v[7].x));
      bHi[jc] = make_uint4(pk2(v[0].y, v[1].y), pk2(v[2].y, v[3].y),
                           pk2(v[4].y, v[5].y), pk2(v[6].y, v[7].y));
    }
  };

  LOAD(0);
  for (int kt = 0; kt < NT; ++kt) {
    __syncthreads();
#pragma unroll
    for (int j = 0; j < 4; ++j)
      *(uint4*)(As + swz(ar, akh * 2 + j * 16)) = aPk[j];
#pragma unroll
    for (int jc = 0; jc < NJC; ++jc) {
      *(uint4*)(Bs + swz(bn,     (bkq * KSPAN + jc * 8) * 2)) = bLo[jc];
      *(uint4*)(Bs + swz(bn + 1, (bkq * KSPAN + jc * 8) * 2)) = bHi[jc];
    }
    __syncthreads();
    if (kt + 1 < NT) LOAD(kt + 1);
#pragma unroll
    for (int kk = 0; kk < 2; ++kk) {
      const int kb = kk * 64 + l16 * 16;
      bf16x8 af[MI], bf[NI];
#pragma unroll
      for (int mi = 0; mi < MI; ++mi)
        af[mi] = *(const bf16x8*)(As + swz(wr * 128 + mi * 16 + ln15, kb));
#pragma unroll
      for (int ni = 0; ni < NI; ++ni)
        bf[ni] = *(const bf16x8*)(Bs + swz(wc * WN + ni * 16 + ln15, kb));
#pragma unroll
      for (int mi = 0; mi < MI; ++mi)
#pragma unroll
        for (int ni = 0; ni < NI; ++ni)
          acc[mi][ni] = __builtin_amdgcn_mfma_f32_16x16x32_bf16(af[mi], bf[ni], acc[mi][ni], 0, 0, 0);
    }
  }

#pragma unroll
  for (int mi = 0; mi < MI; ++mi) {
#pragma unroll
    for (int ni = 0; ni < NI; ++ni) {
      const int col = n0 + wc * WN + ni * 16 + ln15;
#pragma unroll
      for (int j = 0; j < 4; ++j) {
        const int row = m0 + wr * 128 + mi * 16 + l16 * 4 + j;
        float v = acc[mi][ni][j];
        v = v > 0.f ? v : 0.f;
        H[(size_t)(e * CAP + row) * NF + col] = f2bf(v);
      }
    }
  }
}

// ---------------- GEMM2: out[tok] = (H[e] @ w2[e]) * gate --------------
__global__ void __launch_bounds__(512)
gemm2_kernel(const unsigned short* __restrict__ H, const float* __restrict__ W2,
             const int* __restrict__ s2t, const float* __restrict__ gval,
             float* __restrict__ Out) {
  constexpr int BM = 256, BN = 128, BK = 64;
  constexpr int WN = BN / 4;          // 32
  constexpr int MI = 8, NI = WN / 16; // 2
  constexpr int KSPAN = BN / 16;      // 8
  constexpr int NT = NF / BK;         // 64

  __shared__ __align__(16) char lds[BM * 128 + BN * 128];
  char* const As = lds;
  char* const Bs = lds + BM * 128;

  const int tid = threadIdx.x;
  const int lane = tid & 63, wid = tid >> 6;
  const int wr = wid >> 2, wc = wid & 3;
  const int ln15 = lane & 15, l16 = lane >> 4;
  const int e  = blockIdx.z;
  const int m0 = blockIdx.x * BM;
  const int n0 = blockIdx.y * BN;

  const int ar  = tid >> 1;
  const int akh = (tid & 1) * 32;
  const unsigned short* const asrc = H + (size_t)(e * CAP + m0 + ar) * NF + akh;

  const int bn  = (tid & (BN / 2 - 1)) * 2;
  const int bkq = tid / (BN / 2);      // 0..7
  const float* const bsrc = W2 + (size_t)e * NF * DM + (size_t)bkq * KSPAN * DM + n0 + bn;

  f32x4 acc[MI][NI];
#pragma unroll
  for (int mi = 0; mi < MI; ++mi)
#pragma unroll
    for (int ni = 0; ni < NI; ++ni) acc[mi][ni] = f32x4{0.f, 0.f, 0.f, 0.f};

  uint4 aPk[4], bLo, bHi;

  auto LOAD = [&](int kt) {
    const int k0 = kt * BK;
#pragma unroll
    for (int j = 0; j < 4; ++j)
      aPk[j] = *(const uint4*)(asrc + k0 + j * 8);
    const float* bp = bsrc + (size_t)k0 * DM;
    float2 v[8];
#pragma unroll
    for (int r = 0; r < 8; ++r) v[r] = *(const float2*)(bp + (size_t)r * DM);
    bLo = make_uint4(pk2(v[0].x, v[1].x), pk2(v[2].x, v[3].x),
                     pk2(v[4].x, v[5].x), pk2(v[6].x, v[7].x));
    bHi = make_uint4(pk2(v[0].y, v[1].y), pk2(v[2].y, v[3].y),
                     pk2(v[4].y, v[5].y), pk2(v[6].y, v[7].y));
  };

  LOAD(0);
  for (int kt = 0; kt < NT; ++kt) {
    __syncthreads();
#pragma unroll
    for (int j = 0; j < 4; ++j)
      *(uint4*)(As + swz(ar, akh * 2 + j * 16)) = aPk[j];
    *(uint4*)(Bs + swz(bn,     bkq * 16)) = bLo;
    *(uint4*)(Bs + swz(bn + 1, bkq * 16)) = bHi;
    __syncthreads();
    if (kt + 1 < NT) LOAD(kt + 1);
#pragma unroll
    for (int kk = 0; kk < 2; ++kk) {
      const int kb = kk * 64 + l16 * 16;
      bf16x8 af[MI], bf[NI];
#pragma unroll
      for (int mi = 0; mi < MI; ++mi)
        af[mi] = *(const bf16x8*)(As + swz(wr * 128 + mi * 16 + ln15, kb));
#pragma unroll
      for (int ni = 0; ni < NI; ++ni)
        bf[ni] = *(const bf16x8*)(Bs + swz(wc * WN + ni * 16 + ln15, kb));
#pragma unroll
      for (int mi = 0; mi < MI; ++mi)
#pragma unroll
        for (int ni = 0; ni < NI; ++ni)
          acc[mi][ni] = __builtin_amdgcn_mfma_f32_16x16x32_bf16(af[mi], bf[ni], acc[mi][ni], 0, 0, 0);
    }
  }

#pragma unroll
  for (int mi = 0; mi < MI; ++mi) {
#pragma unroll
    for (int ni = 0; ni < NI; ++ni) {
      const int col = n0 + wc * WN + ni * 16 + ln15;
#pragma unroll
      for (int j = 0; j < 4; ++j) {
        const int row = m0 + wr * 128 + mi * 16 + l16 * 4 + j;
        const int tk = s2t[e * CAP + row];
        if (tk >= 0)
          Out[(size_t)tk * DM + col] = acc[mi][ni][j] * gval[tk];
      }
    }
  }
}

// ----------------------------- launcher --------------------------------
extern "C" void kernel_launch(void* const* d_in, const int* in_sizes, int n_in,
                              void* d_out, int out_size, void* d_ws, size_t ws_size,
                              hipStream_t stream) {
  (void)in_sizes; (void)n_in; (void)ws_size;
  const float* X  = (const float*)d_in[0];
  const float* Wg = (const float*)d_in[1];
  const float* W1 = (const float*)d_in[2];
  const float* W2 = (const float*)d_in[3];
  float* Out = (float*)d_out;

  char* ws = (char*)d_ws;
  int*   s2t  = (int*)ws;                          // 8192 ints
  int*   idx  = (int*)(ws + 32768);                // 8192 ints
  float* gval = (float*)(ws + 65536);              // 8192 floats
  unsigned short* H = (unsigned short*)(ws + 98304); // 16*512*4096 bf16 = 64 MB

  hipMemsetAsync(d_out, 0, (size_t)out_size * sizeof(float), stream);
  gate_kernel<<<S_TOK / 16, 256, 0, stream>>>(X, Wg, idx, gval);
  scan_kernel<<<1, 1024, 0, stream>>>(idx, s2t);
  gemm1_kernel<256><<<dim3(2, NF / 256, NE), 512, 0, stream>>>(X, W1, s2t, H);
  gemm2_kernel<<<dim3(2, DM / 128, NE), 512, 0, stream>>>(H, W2, s2t, gval, Out);
}

// Round 2
// 498.267 us; speedup vs baseline: 1.2190x; 1.2190x over previous
//
#include <hip/hip_runtime.h>
#include <cstdint>
#include <cstddef>

#define S_TOK 8192
#define DM    1024
#define NE    16
#define NF    4096
#define CAP   512

typedef __attribute__((ext_vector_type(8))) short bf16x8;
typedef __attribute__((ext_vector_type(4))) float f32x4;

__device__ __forceinline__ unsigned short f2bf(float f) {
  __bf16 b = (__bf16)f;
  return __builtin_bit_cast(unsigned short, b);
}
__device__ __forceinline__ unsigned pk2(float a, float b) {
  return (unsigned)f2bf(a) | ((unsigned)f2bf(b) << 16);
}
// LDS tiles are [row][64 bf16] = 128 B rows; XOR-swizzle to kill 16-way conflicts.
__device__ __forceinline__ int swz(int row, int kbyte) {
  return row * 128 + (kbyte ^ (((row >> 1) & 7) << 4));
}

// ---------------- gating: logits fp32, softmax, argmax -----------------
__global__ void __launch_bounds__(256)
gate_kernel(const float* __restrict__ X, const float* __restrict__ Wg,
            int* __restrict__ idx, float* __restrict__ gval) {
  const int tid  = threadIdx.x;
  const int lane = tid & 63;
  const int wid  = tid >> 6;
  const int e = lane & 15, q = lane >> 4;
  const int t0 = blockIdx.x * 16 + wid * 4;
  const int mbase = q * 256;

  const float* xp0 = X + (size_t)(t0 + 0) * DM + mbase;
  const float* xp1 = X + (size_t)(t0 + 1) * DM + mbase;
  const float* xp2 = X + (size_t)(t0 + 2) * DM + mbase;
  const float* xp3 = X + (size_t)(t0 + 3) * DM + mbase;
  const float* wp  = Wg + (size_t)mbase * NE + e;

  float a0 = 0.f, a1 = 0.f, a2 = 0.f, a3 = 0.f;
#pragma unroll 4
  for (int i = 0; i < 64; ++i) {
    float4 x0 = *(const float4*)(xp0 + i * 4);
    float4 x1 = *(const float4*)(xp1 + i * 4);
    float4 x2 = *(const float4*)(xp2 + i * 4);
    float4 x3 = *(const float4*)(xp3 + i * 4);
    float w0 = wp[(i * 4 + 0) * NE];
    float w1 = wp[(i * 4 + 1) * NE];
    float w2 = wp[(i * 4 + 2) * NE];
    float w3 = wp[(i * 4 + 3) * NE];
    a0 = fmaf(x0.x, w0, fmaf(x0.y, w1, fmaf(x0.z, w2, fmaf(x0.w, w3, a0))));
    a1 = fmaf(x1.x, w0, fmaf(x1.y, w1, fmaf(x1.z, w2, fmaf(x1.w, w3, a1))));
    a2 = fmaf(x2.x, w0, fmaf(x2.y, w1, fmaf(x2.z, w2, fmaf(x2.w, w3, a2))));
    a3 = fmaf(x3.x, w0, fmaf(x3.y, w1, fmaf(x3.z, w2, fmaf(x3.w, w3, a3))));
  }
#pragma unroll
  for (int s = 16; s < 64; s <<= 1) {
    a0 += __shfl_xor(a0, s, 64);
    a1 += __shfl_xor(a1, s, 64);
    a2 += __shfl_xor(a2, s, 64);
    a3 += __shfl_xor(a3, s, 64);
  }
  float l = (q == 0) ? a0 : (q == 1) ? a1 : (q == 2) ? a2 : a3;
  float bv = l; int bi = e;
#pragma unroll
  for (int s = 1; s < 16; s <<= 1) {
    float ov = __shfl_xor(bv, s, 16);
    int   oi = __shfl_xor(bi, s, 16);
    if (ov > bv || (ov == bv && oi < bi)) { bv = ov; bi = oi; }
  }
  float p  = expf(l - bv);
  float sm = p;
#pragma unroll
  for (int s = 1; s < 16; s <<= 1) sm += __shfl_xor(sm, s, 16);
  if (e == 0) {
    idx[t0 + q]  = bi;
    gval[t0 + q] = 1.0f / sm;
  }
}

// ---------------- routing scan: capacity-limited slot assignment -------
__global__ void __launch_bounds__(1024)
scan_kernel(const int* __restrict__ idx, int* __restrict__ s2t) {
  const int tid = threadIdx.x;
#pragma unroll
  for (int k = 0; k < 8; ++k) s2t[tid + k * 1024] = -1;
  __shared__ int base[16];
  __shared__ int wavecnt[16][16];
  if (tid < 16) base[tid] = 0;
  __syncthreads();
  const int wid = tid >> 6, lane = tid & 63;
  const unsigned long long ltmask = (1ull << lane) - 1ull;
  for (int c = 0; c < 8; ++c) {
    const int t = c * 1024 + tid;
    const int e = idx[t];
    int rank = 0;
#pragma unroll
    for (int ee = 0; ee < 16; ++ee) {
      unsigned long long m = __ballot(e == ee);
      if (lane == 0) wavecnt[wid][ee] = __popcll(m);
      if (ee == e) rank = __popcll(m & ltmask);
    }
    __syncthreads();
    if (tid < 16) {
      int s = base[tid];
#pragma unroll
      for (int w = 0; w < 16; ++w) { int cc = wavecnt[w][tid]; wavecnt[w][tid] = s; s += cc; }
      base[tid] = s;
    }
    __syncthreads();
    const int loc = wavecnt[wid][e] + rank;
    if (loc < CAP) s2t[e * CAP + loc] = t;
    __syncthreads();
  }
}

// ---------------- GEMM1: H[e] = relu(gather(x)[e] @ w1[e]) -------------
// 128x128 tile, BK=64, 256 threads (4 waves, 2x2), m97 structure.
#define G1_GX 4
#define G1_GY 32
#define G1_GZ 16
__global__ void __launch_bounds__(256, 3)
gemm1_kernel(const float* __restrict__ X, const float* __restrict__ W1,
             const int* __restrict__ s2t, unsigned short* __restrict__ H) {
  constexpr int BM = 128, BN = 128, BK = 64;
  constexpr int NT = DM / BK;   // 16

  __shared__ __align__(16) char lds[BM * 128 + BN * 128];  // 32 KB
  char* const As = lds;
  char* const Bs = lds + BM * 128;

  const int tid = threadIdx.x;
  const int lane = tid & 63, wid = tid >> 6;
  const int wr = wid >> 1, wc = wid & 1;
  const int ln15 = lane & 15, l16 = lane >> 4;

  // XCD-aware bijective swizzle (nwg = 2048, cpx = 256)
  int flat = blockIdx.x + G1_GX * (blockIdx.y + G1_GY * blockIdx.z);
  flat = (flat & 7) * (G1_GX * G1_GY * G1_GZ / 8) + (flat >> 3);
  const int bx = flat % G1_GX;
  const int by = (flat / G1_GX) % G1_GY;
  const int e  = flat / (G1_GX * G1_GY);
  const int m0 = bx * BM;
  const int n0 = by * BN;

  const int ar  = tid >> 1;            // A row 0..127
  const int akh = (tid & 1) * 32;      // fp32 k-half
  const int tok = s2t[e * CAP + m0 + ar];
  const float* const asrc = X + (size_t)(tok < 0 ? 0 : tok) * DM + akh;

  const int bn4 = (tid & 31) * 4;      // B col group (4 cols)
  const int bkq = tid >> 5;            // 0..7, 8 k-rows each
  const float* const bsrc = W1 + (size_t)e * DM * NF + (size_t)(bkq * 8) * NF + n0 + bn4;

  f32x4 acc[4][4];
#pragma unroll
  for (int mi = 0; mi < 4; ++mi)
#pragma unroll
    for (int ni = 0; ni < 4; ++ni) acc[mi][ni] = f32x4{0.f, 0.f, 0.f, 0.f};

  uint4 aPk[4], bPk[4];

  auto LOAD = [&](int kt) {
    const int k0 = kt * BK;
    if (tok >= 0) {
#pragma unroll
      for (int j = 0; j < 4; ++j) {
        float4 v0 = *(const float4*)(asrc + k0 + j * 8);
        float4 v1 = *(const float4*)(asrc + k0 + j * 8 + 4);
        aPk[j] = make_uint4(pk2(v0.x, v0.y), pk2(v0.z, v0.w),
                            pk2(v1.x, v1.y), pk2(v1.z, v1.w));
      }
    } else {
#pragma unroll
      for (int j = 0; j < 4; ++j) aPk[j] = make_uint4(0u, 0u, 0u, 0u);
    }
    const float* bp = bsrc + (size_t)k0 * NF;
    float4 w[8];
#pragma unroll
    for (int r = 0; r < 8; ++r) w[r] = *(const float4*)(bp + (size_t)r * NF);
    const float* wf = (const float*)w;
#pragma unroll
    for (int c = 0; c < 4; ++c)
      bPk[c] = make_uint4(pk2(wf[0 * 4 + c], wf[1 * 4 + c]),
                          pk2(wf[2 * 4 + c], wf[3 * 4 + c]),
                          pk2(wf[4 * 4 + c], wf[5 * 4 + c]),
                          pk2(wf[6 * 4 + c], wf[7 * 4 + c]));
  };

  LOAD(0);
  for (int kt = 0; kt < NT; ++kt) {
    __syncthreads();
#pragma unroll
    for (int j = 0; j < 4; ++j)
      *(uint4*)(As + swz(ar, akh * 2 + j * 16)) = aPk[j];
#pragma unroll
    for (int c = 0; c < 4; ++c)
      *(uint4*)(Bs + swz(bn4 + c, bkq * 16)) = bPk[c];
    __syncthreads();
    if (kt + 1 < NT) LOAD(kt + 1);
#pragma unroll
    for (int kk = 0; kk < 2; ++kk) {
      const int kb = kk * 64 + l16 * 16;
      bf16x8 af[4], bf[4];
#pragma unroll
      for (int mi = 0; mi < 4; ++mi)
        af[mi] = *(const bf16x8*)(As + swz(wr * 64 + mi * 16 + ln15, kb));
#pragma unroll
      for (int ni = 0; ni < 4; ++ni)
        bf[ni] = *(const bf16x8*)(Bs + swz(wc * 64 + ni * 16 + ln15, kb));
#pragma unroll
      for (int mi = 0; mi < 4; ++mi)
#pragma unroll
        for (int ni = 0; ni < 4; ++ni)
          acc[mi][ni] = __builtin_amdgcn_mfma_f32_16x16x32_bf16(af[mi], bf[ni], acc[mi][ni], 0, 0, 0);
    }
  }

#pragma unroll
  for (int mi = 0; mi < 4; ++mi) {
#pragma unroll
    for (int ni = 0; ni < 4; ++ni) {
      const int col = n0 + wc * 64 + ni * 16 + ln15;
#pragma unroll
      for (int j = 0; j < 4; ++j) {
        const int row = m0 + wr * 64 + mi * 16 + l16 * 4 + j;
        float v = acc[mi][ni][j];
        v = v > 0.f ? v : 0.f;
        H[(size_t)(e * CAP + row) * NF + col] = f2bf(v);
      }
    }
  }
}

// ---------------- GEMM2: out[tok] = (H[e] @ w2[e]) * gate --------------
// 128x128 tile, BK=64, 256 threads (4 waves, 2x2).
#define G2_GX 4
#define G2_GY 8
#define G2_GZ 16
__global__ void __launch_bounds__(256, 2)
gemm2_kernel(const unsigned short* __restrict__ H, const float* __restrict__ W2,
             const int* __restrict__ s2t, const float* __restrict__ gval,
             float* __restrict__ Out) {
  constexpr int BM = 128, BN = 128, BK = 64;
  constexpr int NT = NF / BK;   // 64

  __shared__ __align__(16) char lds[BM * 128 + BN * 128];  // 32 KB
  char* const As = lds;
  char* const Bs = lds + BM * 128;

  const int tid = threadIdx.x;
  const int lane = tid & 63, wid = tid >> 6;
  const int wr = wid >> 1, wc = wid & 1;
  const int ln15 = lane & 15, l16 = lane >> 4;

  // XCD-aware bijective swizzle (nwg = 512, cpx = 64)
  int flat = blockIdx.x + G2_GX * (blockIdx.y + G2_GY * blockIdx.z);
  flat = (flat & 7) * (G2_GX * G2_GY * G2_GZ / 8) + (flat >> 3);
  const int bx = flat % G2_GX;
  const int by = (flat / G2_GX) % G2_GY;
  const int e  = flat / (G2_GX * G2_GY);
  const int m0 = bx * BM;
  const int n0 = by * BN;

  const int ar  = tid >> 1;            // A row 0..127
  const int akh = (tid & 1) * 32;      // bf16 k-half (32 shorts = 64 B)
  const unsigned short* const asrc = H + (size_t)(e * CAP + m0 + ar) * NF + akh;

  const int bn4 = (tid & 31) * 4;
  const int bkq = tid >> 5;
  const float* const bsrc = W2 + (size_t)e * NF * DM + (size_t)(bkq * 8) * DM + n0 + bn4;

  f32x4 acc[4][4];
#pragma unroll
  for (int mi = 0; mi < 4; ++mi)
#pragma unroll
    for (int ni = 0; ni < 4; ++ni) acc[mi][ni] = f32x4{0.f, 0.f, 0.f, 0.f};

  uint4 aPk[4], bPk[4];

  auto LOAD = [&](int kt) {
    const int k0 = kt * BK;
#pragma unroll
    for (int j = 0; j < 4; ++j)
      aPk[j] = *(const uint4*)(asrc + k0 + j * 8);
    const float* bp = bsrc + (size_t)k0 * DM;
    float4 w[8];
#pragma unroll
    for (int r = 0; r < 8; ++r) w[r] = *(const float4*)(bp + (size_t)r * DM);
    const float* wf = (const float*)w;
#pragma unroll
    for (int c = 0; c < 4; ++c)
      bPk[c] = make_uint4(pk2(wf[0 * 4 + c], wf[1 * 4 + c]),
                          pk2(wf[2 * 4 + c], wf[3 * 4 + c]),
                          pk2(wf[4 * 4 + c], wf[5 * 4 + c]),
                          pk2(wf[6 * 4 + c], wf[7 * 4 + c]));
  };

  LOAD(0);
  for (int kt = 0; kt < NT; ++kt) {
    __syncthreads();
#pragma unroll
    for (int j = 0; j < 4; ++j)
      *(uint4*)(As + swz(ar, akh * 2 + j * 16)) = aPk[j];
#pragma unroll
    for (int c = 0; c < 4; ++c)
      *(uint4*)(Bs + swz(bn4 + c, bkq * 16)) = bPk[c];
    __syncthreads();
    if (kt + 1 < NT) LOAD(kt + 1);
#pragma unroll
    for (int kk = 0; kk < 2; ++kk) {
      const int kb = kk * 64 + l16 * 16;
      bf16x8 af[4], bf[4];
#pragma unroll
      for (int mi = 0; mi < 4; ++mi)
        af[mi] = *(const bf16x8*)(As + swz(wr * 64 + mi * 16 + ln15, kb));
#pragma unroll
      for (int ni = 0; ni < 4; ++ni)
        bf[ni] = *(const bf16x8*)(Bs + swz(wc * 64 + ni * 16 + ln15, kb));
#pragma unroll
      for (int mi = 0; mi < 4; ++mi)
#pragma unroll
        for (int ni = 0; ni < 4; ++ni)
          acc[mi][ni] = __builtin_amdgcn_mfma_f32_16x16x32_bf16(af[mi], bf[ni], acc[mi][ni], 0, 0, 0);
    }
  }

#pragma unroll
  for (int mi = 0; mi < 4; ++mi) {
#pragma unroll
    for (int ni = 0; ni < 4; ++ni) {
      const int col = n0 + wc * 64 + ni * 16 + ln15;
#pragma unroll
      for (int j = 0; j < 4; ++j) {
        const int row = m0 + wr * 64 + mi * 16 + l16 * 4 + j;
        const int tk = s2t[e * CAP + row];
        if (tk >= 0)
          Out[(size_t)tk * DM + col] = acc[mi][ni][j] * gval[tk];
      }
    }
  }
}

// ----------------------------- launcher --------------------------------
extern "C" void kernel_launch(void* const* d_in, const int* in_sizes, int n_in,
                              void* d_out, int out_size, void* d_ws, size_t ws_size,
                              hipStream_t stream) {
  (void)in_sizes; (void)n_in; (void)ws_size;
  const float* X  = (const float*)d_in[0];
  const float* Wg = (const float*)d_in[1];
  const float* W1 = (const float*)d_in[2];
  const float* W2 = (const float*)d_in[3];
  float* Out = (float*)d_out;

  char* ws = (char*)d_ws;
  int*   s2t  = (int*)ws;                            // 8192 ints
  int*   idx  = (int*)(ws + 32768);                  // 8192 ints
  float* gval = (float*)(ws + 65536);                // 8192 floats
  unsigned short* H = (unsigned short*)(ws + 98304); // 16*512*4096 bf16 = 64 MB

  hipMemsetAsync(d_out, 0, (size_t)out_size * sizeof(float), stream);
  gate_kernel<<<S_TOK / 16, 256, 0, stream>>>(X, Wg, idx, gval);
  scan_kernel<<<1, 1024, 0, stream>>>(idx, s2t);
  gemm1_kernel<<<dim3(G1_GX, G1_GY, G1_GZ), 256, 0, stream>>>(X, W1, s2t, H);
  gemm2_kernel<<<dim3(G2_GX, G2_GY, G2_GZ), 256, 0, stream>>>(H, W2, s2t, gval, Out);
}

// Round 3
// 388.073 us; speedup vs baseline: 1.5651x; 1.2840x over previous
//
#include <hip/hip_runtime.h>
#include <cstdint>
#include <cstddef>

#define S_TOK 8192
#define DM    1024
#define NE    16
#define NF    4096
#define CAP   512

typedef __attribute__((ext_vector_type(8))) short bf16x8;
typedef __attribute__((ext_vector_type(4))) float f32x4;

__device__ __forceinline__ unsigned short f2bf(float f) {
  __bf16 b = (__bf16)f;
  return __builtin_bit_cast(unsigned short, b);
}
__device__ __forceinline__ unsigned pk2(float a, float b) {
  return (unsigned)f2bf(a) | ((unsigned)f2bf(b) << 16);
}
// bank-spread for the B [kg][col][16B] LDS layout
__device__ __forceinline__ int pcol(int c) { return c ^ ((c >> 3) & 7); }

__device__ __forceinline__ void gload_lds16(const void* g, void* l) {
  __builtin_amdgcn_global_load_lds(
      (const __attribute__((address_space(1))) void*)g,
      (__attribute__((address_space(3))) void*)l, 16, 0, 0);
}

// ---------------- gating: logits fp32, softmax, argmax -----------------
__global__ void __launch_bounds__(256)
gate_kernel(const float* __restrict__ X, const float* __restrict__ Wg,
            int* __restrict__ idx, float* __restrict__ gval) {
  const int tid  = threadIdx.x;
  const int lane = tid & 63;
  const int wid  = tid >> 6;
  const int e = lane & 15, q = lane >> 4;
  const int t0 = blockIdx.x * 16 + wid * 4;
  const int mbase = q * 256;

  const float* xp0 = X + (size_t)(t0 + 0) * DM + mbase;
  const float* xp1 = X + (size_t)(t0 + 1) * DM + mbase;
  const float* xp2 = X + (size_t)(t0 + 2) * DM + mbase;
  const float* xp3 = X + (size_t)(t0 + 3) * DM + mbase;
  const float* wp  = Wg + (size_t)mbase * NE + e;

  float a0 = 0.f, a1 = 0.f, a2 = 0.f, a3 = 0.f;
#pragma unroll 4
  for (int i = 0; i < 64; ++i) {
    float4 x0 = *(const float4*)(xp0 + i * 4);
    float4 x1 = *(const float4*)(xp1 + i * 4);
    float4 x2 = *(const float4*)(xp2 + i * 4);
    float4 x3 = *(const float4*)(xp3 + i * 4);
    float w0 = wp[(i * 4 + 0) * NE];
    float w1 = wp[(i * 4 + 1) * NE];
    float w2 = wp[(i * 4 + 2) * NE];
    float w3 = wp[(i * 4 + 3) * NE];
    a0 = fmaf(x0.x, w0, fmaf(x0.y, w1, fmaf(x0.z, w2, fmaf(x0.w, w3, a0))));
    a1 = fmaf(x1.x, w0, fmaf(x1.y, w1, fmaf(x1.z, w2, fmaf(x1.w, w3, a1))));
    a2 = fmaf(x2.x, w0, fmaf(x2.y, w1, fmaf(x2.z, w2, fmaf(x2.w, w3, a2))));
    a3 = fmaf(x3.x, w0, fmaf(x3.y, w1, fmaf(x3.z, w2, fmaf(x3.w, w3, a3))));
  }
#pragma unroll
  for (int s = 16; s < 64; s <<= 1) {
    a0 += __shfl_xor(a0, s, 64);
    a1 += __shfl_xor(a1, s, 64);
    a2 += __shfl_xor(a2, s, 64);
    a3 += __shfl_xor(a3, s, 64);
  }
  float l = (q == 0) ? a0 : (q == 1) ? a1 : (q == 2) ? a2 : a3;
  float bv = l; int bi = e;
#pragma unroll
  for (int s = 1; s < 16; s <<= 1) {
    float ov = __shfl_xor(bv, s, 16);
    int   oi = __shfl_xor(bi, s, 16);
    if (ov > bv || (ov == bv && oi < bi)) { bv = ov; bi = oi; }
  }
  float p  = expf(l - bv);
  float sm = p;
#pragma unroll
  for (int s = 1; s < 16; s <<= 1) sm += __shfl_xor(sm, s, 16);
  if (e == 0) {
    idx[t0 + q]  = bi;
    gval[t0 + q] = 1.0f / sm;
  }
}

// ---------------- routing scan: capacity-limited slot assignment -------
__global__ void __launch_bounds__(1024)
scan_kernel(const int* __restrict__ idx, int* __restrict__ s2t) {
  const int tid = threadIdx.x;
#pragma unroll
  for (int k = 0; k < 8; ++k) s2t[tid + k * 1024] = -1;
  __shared__ int base[16];
  __shared__ int wavecnt[16][16];
  if (tid < 16) base[tid] = 0;
  __syncthreads();
  const int wid = tid >> 6, lane = tid & 63;
  const unsigned long long ltmask = (1ull << lane) - 1ull;
  for (int c = 0; c < 8; ++c) {
    const int t = c * 1024 + tid;
    const int e = idx[t];
    int rank = 0;
#pragma unroll
    for (int ee = 0; ee < 16; ++ee) {
      unsigned long long m = __ballot(e == ee);
      if (lane == 0) wavecnt[wid][ee] = __popcll(m);
      if (ee == e) rank = __popcll(m & ltmask);
    }
    __syncthreads();
    if (tid < 16) {
      int s = base[tid];
#pragma unroll
      for (int w = 0; w < 16; ++w) { int cc = wavecnt[w][tid]; wavecnt[w][tid] = s; s += cc; }
      base[tid] = s;
    }
    __syncthreads();
    const int loc = wavecnt[wid][e] + rank;
    if (loc < CAP) s2t[e * CAP + loc] = t;
    __syncthreads();
  }
}

// H2 layout: [e][kt(64)][kg(8)][row(512)][8 bf16]; per-expert 4 MB.
// byte(e,kt,kg,row,el) = e*4194304 + kt*65536 + kg*8192 + row*16 + el*2

// ---------------- GEMM1: H2[e] = relu(gather(x)[e] @ w1[e]) ------------
// 128x128 tile, BK=64, 256 thr (4 waves 2x2), dbuf LDS, 1 barrier/iter.
#define G1_GX 4
#define G1_GY 32
#define G1_GZ 16
__global__ void __launch_bounds__(256, 2)
gemm1_kernel(const float* __restrict__ X, const float* __restrict__ W1,
             const int* __restrict__ s2t, unsigned short* __restrict__ H2) {
  constexpr int NT = DM / 64;  // 16
  // buffer: [A: (kg*128+row)*16, 16KB][B: 16384 + (kg*128+pcol)*16, 16KB]
  __shared__ __align__(16) char lds[2][32768];

  const int tid = threadIdx.x;
  const int lane = tid & 63, wid = tid >> 6;
  const int wr = wid >> 1, wc = wid & 1;
  const int ln15 = lane & 15, l16 = lane >> 4;

  int flat = blockIdx.x + G1_GX * (blockIdx.y + G1_GY * blockIdx.z);
  flat = (flat & 7) * (G1_GX * G1_GY * G1_GZ / 8) + (flat >> 3);
  const int bx = flat % G1_GX;
  const int by = (flat / G1_GX) % G1_GY;
  const int e  = flat / (G1_GX * G1_GY);
  const int m0 = bx * 128, n0 = by * 128;

  // A staging (reg, cvt): thread covers row ar, k-half kg0..kg0+3
  const int ar  = tid >> 1;
  const int kg0 = (tid & 1) * 4;
  const int tok = s2t[e * CAP + m0 + ar];
  const float* const asrc = X + (size_t)(tok < 0 ? 0 : tok) * DM + kg0 * 8;
  // B staging: 4 cols c0.., k-rows kgB*8..+8
  const int c0  = (tid & 31) * 4;
  const int kgB = tid >> 5;
  const float* const bsrc = W1 + (size_t)e * DM * NF + (size_t)(kgB * 8) * NF + n0 + c0;

  int awoff[4], bwoff[4], aoff[4], boff[4];
#pragma unroll
  for (int j = 0; j < 4; ++j) awoff[j] = ((kg0 + j) * 128 + ar) * 16;
#pragma unroll
  for (int cc = 0; cc < 4; ++cc) bwoff[cc] = 16384 + (kgB * 128 + pcol(c0 + cc)) * 16;
#pragma unroll
  for (int mi = 0; mi < 4; ++mi) aoff[mi] = l16 * 2048 + (wr * 64 + mi * 16 + ln15) * 16;
#pragma unroll
  for (int ni = 0; ni < 4; ++ni) boff[ni] = 16384 + l16 * 2048 + pcol(wc * 64 + ni * 16 + ln15) * 16;

  f32x4 acc[4][4];
#pragma unroll
  for (int mi = 0; mi < 4; ++mi)
#pragma unroll
    for (int ni = 0; ni < 4; ++ni) acc[mi][ni] = f32x4{0.f, 0.f, 0.f, 0.f};

  auto STAGE = [&](char* buf, int kt) {
    const float* ap = asrc + kt * 64;
#pragma unroll
    for (int j = 0; j < 4; ++j) {
      float4 v0 = *(const float4*)(ap + j * 8);
      float4 v1 = *(const float4*)(ap + j * 8 + 4);
      *(uint4*)(buf + awoff[j]) = make_uint4(pk2(v0.x, v0.y), pk2(v0.z, v0.w),
                                             pk2(v1.x, v1.y), pk2(v1.z, v1.w));
    }
    const float* bp = bsrc + (size_t)kt * 64 * NF;
#pragma unroll
    for (int h = 0; h < 2; ++h) {
      float4 r0 = *(const float4*)(bp + (size_t)(h * 4 + 0) * NF);
      float4 r1 = *(const float4*)(bp + (size_t)(h * 4 + 1) * NF);
      float4 r2 = *(const float4*)(bp + (size_t)(h * 4 + 2) * NF);
      float4 r3 = *(const float4*)(bp + (size_t)(h * 4 + 3) * NF);
      const float* f0 = (const float*)&r0; const float* f1 = (const float*)&r1;
      const float* f2 = (const float*)&r2; const float* f3 = (const float*)&r3;
#pragma unroll
      for (int cc = 0; cc < 4; ++cc)
        *(uint2*)(buf + bwoff[cc] + h * 8) =
            make_uint2(pk2(f0[cc], f1[cc]), pk2(f2[cc], f3[cc]));
    }
  };

  auto COMPUTE = [&](const char* buf) {
#pragma unroll
    for (int kk = 0; kk < 2; ++kk) {
      bf16x8 af[4], bf[4];
#pragma unroll
      for (int mi = 0; mi < 4; ++mi)
        af[mi] = *(const bf16x8*)(buf + kk * 8192 + aoff[mi]);
#pragma unroll
      for (int ni = 0; ni < 4; ++ni)
        bf[ni] = *(const bf16x8*)(buf + kk * 8192 + boff[ni]);
#pragma unroll
      for (int mi = 0; mi < 4; ++mi)
#pragma unroll
        for (int ni = 0; ni < 4; ++ni)
          acc[mi][ni] = __builtin_amdgcn_mfma_f32_16x16x32_bf16(af[mi], bf[ni], acc[mi][ni], 0, 0, 0);
    }
  };

  STAGE(lds[0], 0);
  __syncthreads();
  int cur = 0;
  for (int kt = 0; kt < NT; ++kt) {
    if (kt + 1 < NT) STAGE(lds[cur ^ 1], kt + 1);
    COMPUTE(lds[cur]);
    __syncthreads();
    cur ^= 1;
  }

  // ---- epilogue: relu, LDS transpose to H2-image, contiguous stores ----
  char* img = lds[0];
#pragma unroll
  for (int mi = 0; mi < 4; ++mi) {
#pragma unroll
    for (int ni = 0; ni < 4; ++ni) {
      const int colL = wc * 64 + ni * 16 + ln15;
      const int base = ((colL >> 6) * 8 + ((colL >> 3) & 7)) * 2048 + (colL & 7) * 2;
#pragma unroll
      for (int j = 0; j < 4; ++j) {
        const int rowL = wr * 64 + mi * 16 + l16 * 4 + j;
        float v = acc[mi][ni][j];
        v = v > 0.f ? v : 0.f;
        *(unsigned short*)(img + base + rowL * 16) = f2bf(v);
      }
    }
  }
  __syncthreads();
  const char* src = img + tid * 128;
  const size_t g = (size_t)e * 4194304 + (size_t)(n0 >> 6) * 65536 +
                   (size_t)(tid >> 7) * 65536 + (size_t)((tid >> 4) & 7) * 8192 +
                   (size_t)(m0 + (tid & 15) * 8) * 16;
  char* dst = (char*)H2 + g;
#pragma unroll
  for (int u = 0; u < 8; ++u)
    *(uint4*)(dst + u * 16) = *(const uint4*)(src + u * 16);
}

// ---------------- GEMM2: out[tok] = (H2[e] @ w2[e]) * gate -------------
// A via global_load_lds (zero-reg staging), B reg-staged fp32->bf16.
#define G2_GX 4
#define G2_GY 8
#define G2_GZ 16
__global__ void __launch_bounds__(256, 2)
gemm2_kernel(const unsigned short* __restrict__ H2, const float* __restrict__ W2,
             const int* __restrict__ s2t, const float* __restrict__ gval,
             float* __restrict__ Out) {
  constexpr int NT = NF / 64;  // 64
  __shared__ __align__(16) char lds[2][32768];

  const int tid = threadIdx.x;
  const int lane = tid & 63, wid = tid >> 6;
  const int wr = wid >> 1, wc = wid & 1;
  const int ln15 = lane & 15, l16 = lane >> 4;

  int flat = blockIdx.x + G2_GX * (blockIdx.y + G2_GY * blockIdx.z);
  flat = (flat & 7) * (G2_GX * G2_GY * G2_GZ / 8) + (flat >> 3);
  const int bx = flat % G2_GX;
  const int by = (flat / G2_GX) % G2_GY;
  const int e  = flat / (G2_GX * G2_GY);
  const int m0 = bx * 128, n0 = by * 128;

  // A: H2 blocked source; per issue q: kg=q>>1, rows (q&1)*64+lane
  const char* const Hex = (const char*)H2 + (size_t)e * 4194304 + (size_t)m0 * 16;
  // B staging
  const int c0  = (tid & 31) * 4;
  const int kgB = tid >> 5;
  const float* const bsrc = W2 + (size_t)e * NF * DM + (size_t)(kgB * 8) * DM + n0 + c0;

  int bwoff[4], aoff[4], boff[4];
#pragma unroll
  for (int cc = 0; cc < 4; ++cc) bwoff[cc] = 16384 + (kgB * 128 + pcol(c0 + cc)) * 16;
#pragma unroll
  for (int mi = 0; mi < 4; ++mi) aoff[mi] = l16 * 2048 + (wr * 64 + mi * 16 + ln15) * 16;
#pragma unroll
  for (int ni = 0; ni < 4; ++ni) boff[ni] = 16384 + l16 * 2048 + pcol(wc * 64 + ni * 16 + ln15) * 16;

  f32x4 acc[4][4];
#pragma unroll
  for (int mi = 0; mi < 4; ++mi)
#pragma unroll
    for (int ni = 0; ni < 4; ++ni) acc[mi][ni] = f32x4{0.f, 0.f, 0.f, 0.f};

  auto STAGE = [&](char* buf, int kt) {
#pragma unroll
    for (int i = 0; i < 4; ++i) {
      const int q = i * 4 + wid;
      const char* gp = Hex + (size_t)kt * 65536 + (size_t)(q >> 1) * 8192 +
                       (size_t)((q & 1) * 64 + lane) * 16;
      gload_lds16(gp, buf + q * 1024);
    }
    const float* bp = bsrc + (size_t)kt * 64 * DM;
#pragma unroll
    for (int h = 0; h < 2; ++h) {
      float4 r0 = *(const float4*)(bp + (size_t)(h * 4 + 0) * DM);
      float4 r1 = *(const float4*)(bp + (size_t)(h * 4 + 1) * DM);
      float4 r2 = *(const float4*)(bp + (size_t)(h * 4 + 2) * DM);
      float4 r3 = *(const float4*)(bp + (size_t)(h * 4 + 3) * DM);
      const float* f0 = (const float*)&r0; const float* f1 = (const float*)&r1;
      const float* f2 = (const float*)&r2; const float* f3 = (const float*)&r3;
#pragma unroll
      for (int cc = 0; cc < 4; ++cc)
        *(uint2*)(buf + bwoff[cc] + h * 8) =
            make_uint2(pk2(f0[cc], f1[cc]), pk2(f2[cc], f3[cc]));
    }
  };

  auto COMPUTE = [&](const char* buf) {
#pragma unroll
    for (int kk = 0; kk < 2; ++kk) {
      bf16x8 af[4], bf[4];
#pragma unroll
      for (int mi = 0; mi < 4; ++mi)
        af[mi] = *(const bf16x8*)(buf + kk * 8192 + aoff[mi]);
#pragma unroll
      for (int ni = 0; ni < 4; ++ni)
        bf[ni] = *(const bf16x8*)(buf + kk * 8192 + boff[ni]);
#pragma unroll
      for (int mi = 0; mi < 4; ++mi)
#pragma unroll
        for (int ni = 0; ni < 4; ++ni)
          acc[mi][ni] = __builtin_amdgcn_mfma_f32_16x16x32_bf16(af[mi], bf[ni], acc[mi][ni], 0, 0, 0);
    }
  };

  STAGE(lds[0], 0);
  __syncthreads();
  int cur = 0;
  for (int kt = 0; kt < NT; ++kt) {
    if (kt + 1 < NT) STAGE(lds[cur ^ 1], kt + 1);
    COMPUTE(lds[cur]);
    __syncthreads();
    cur ^= 1;
  }

#pragma unroll
  for (int mi = 0; mi < 4; ++mi) {
#pragma unroll
    for (int ni = 0; ni < 4; ++ni) {
      const int col = n0 + wc * 64 + ni * 16 + ln15;
#pragma unroll
      for (int j = 0; j < 4; ++j) {
        const int row = m0 + wr * 64 + mi * 16 + l16 * 4 + j;
        const int tk = s2t[e * CAP + row];
        if (tk >= 0)
          Out[(size_t)tk * DM + col] = acc[mi][ni][j] * gval[tk];
      }
    }
  }
}

// ----------------------------- launcher --------------------------------
extern "C" void kernel_launch(void* const* d_in, const int* in_sizes, int n_in,
                              void* d_out, int out_size, void* d_ws, size_t ws_size,
                              hipStream_t stream) {
  (void)in_sizes; (void)n_in; (void)ws_size;
  const float* X  = (const float*)d_in[0];
  const float* Wg = (const float*)d_in[1];
  const float* W1 = (const float*)d_in[2];
  const float* W2 = (const float*)d_in[3];
  float* Out = (float*)d_out;

  char* ws = (char*)d_ws;
  int*   s2t  = (int*)ws;                            // 8192 ints
  int*   idx  = (int*)(ws + 32768);                  // 8192 ints
  float* gval = (float*)(ws + 65536);                // 8192 floats
  unsigned short* H2 = (unsigned short*)(ws + 98304); // 64 MB blocked layout

  hipMemsetAsync(d_out, 0, (size_t)out_size * sizeof(float), stream);
  gate_kernel<<<S_TOK / 16, 256, 0, stream>>>(X, Wg, idx, gval);
  scan_kernel<<<1, 1024, 0, stream>>>(idx, s2t);
  gemm1_kernel<<<dim3(G1_GX, G1_GY, G1_GZ), 256, 0, stream>>>(X, W1, s2t, H2);
  gemm2_kernel<<<dim3(G2_GX, G2_GY, G2_GZ), 256, 0, stream>>>(H2, W2, s2t, gval, Out);
}

// Round 4
// 371.635 us; speedup vs baseline: 1.6343x; 1.0442x over previous
//
#include <hip/hip_runtime.h>
#include <cstdint>
#include <cstddef>

#define S_TOK 8192
#define DM    1024
#define NE    16
#define NF    4096
#define CAP   512

typedef __attribute__((ext_vector_type(8))) short bf16x8;
typedef __attribute__((ext_vector_type(4))) float f32x4;

__device__ __forceinline__ unsigned short f2bf(float f) {
  __bf16 b = (__bf16)f;
  return __builtin_bit_cast(unsigned short, b);
}
__device__ __forceinline__ unsigned pk2(float a, float b) {
  return (unsigned)f2bf(a) | ((unsigned)f2bf(b) << 16);
}
// bank-spread for the B [kg][col][16B] LDS layout
__device__ __forceinline__ int pcol(int c) { return c ^ ((c >> 3) & 7); }

__device__ __forceinline__ void gload_lds16(const void* g, void* l) {
  __builtin_amdgcn_global_load_lds(
      (const __attribute__((address_space(1))) void*)g,
      (__attribute__((address_space(3))) void*)l, 16, 0, 0);
}

// ---------------- X fp32 -> bf16 convert (one pass) --------------------
__global__ void __launch_bounds__(256)
cvt_kernel(const float* __restrict__ X, unsigned short* __restrict__ Xb) {
  const int t = blockIdx.x * 256 + threadIdx.x;   // 16 elems per thread
  const float4* src = (const float4*)X + (size_t)t * 4;
  float4 v0 = src[0], v1 = src[1], v2 = src[2], v3 = src[3];
  uint4 o0 = make_uint4(pk2(v0.x, v0.y), pk2(v0.z, v0.w),
                        pk2(v1.x, v1.y), pk2(v1.z, v1.w));
  uint4 o1 = make_uint4(pk2(v2.x, v2.y), pk2(v2.z, v2.w),
                        pk2(v3.x, v3.y), pk2(v3.z, v3.w));
  uint4* dst = (uint4*)Xb + (size_t)t * 2;
  dst[0] = o0; dst[1] = o1;
}

// ---------------- gating: logits fp32, softmax, argmax -----------------
__global__ void __launch_bounds__(256)
gate_kernel(const float* __restrict__ X, const float* __restrict__ Wg,
            int* __restrict__ idx, float* __restrict__ gval) {
  const int tid  = threadIdx.x;
  const int lane = tid & 63;
  const int wid  = tid >> 6;
  const int e = lane & 15, q = lane >> 4;
  const int t0 = blockIdx.x * 16 + wid * 4;
  const int mbase = q * 256;

  const float* xp0 = X + (size_t)(t0 + 0) * DM + mbase;
  const float* xp1 = X + (size_t)(t0 + 1) * DM + mbase;
  const float* xp2 = X + (size_t)(t0 + 2) * DM + mbase;
  const float* xp3 = X + (size_t)(t0 + 3) * DM + mbase;
  const float* wp  = Wg + (size_t)mbase * NE + e;

  float a0 = 0.f, a1 = 0.f, a2 = 0.f, a3 = 0.f;
#pragma unroll 4
  for (int i = 0; i < 64; ++i) {
    float4 x0 = *(const float4*)(xp0 + i * 4);
    float4 x1 = *(const float4*)(xp1 + i * 4);
    float4 x2 = *(const float4*)(xp2 + i * 4);
    float4 x3 = *(const float4*)(xp3 + i * 4);
    float w0 = wp[(i * 4 + 0) * NE];
    float w1 = wp[(i * 4 + 1) * NE];
    float w2 = wp[(i * 4 + 2) * NE];
    float w3 = wp[(i * 4 + 3) * NE];
    a0 = fmaf(x0.x, w0, fmaf(x0.y, w1, fmaf(x0.z, w2, fmaf(x0.w, w3, a0))));
    a1 = fmaf(x1.x, w0, fmaf(x1.y, w1, fmaf(x1.z, w2, fmaf(x1.w, w3, a1))));
    a2 = fmaf(x2.x, w0, fmaf(x2.y, w1, fmaf(x2.z, w2, fmaf(x2.w, w3, a2))));
    a3 = fmaf(x3.x, w0, fmaf(x3.y, w1, fmaf(x3.z, w2, fmaf(x3.w, w3, a3))));
  }
#pragma unroll
  for (int s = 16; s < 64; s <<= 1) {
    a0 += __shfl_xor(a0, s, 64);
    a1 += __shfl_xor(a1, s, 64);
    a2 += __shfl_xor(a2, s, 64);
    a3 += __shfl_xor(a3, s, 64);
  }
  float l = (q == 0) ? a0 : (q == 1) ? a1 : (q == 2) ? a2 : a3;
  float bv = l; int bi = e;
#pragma unroll
  for (int s = 1; s < 16; s <<= 1) {
    float ov = __shfl_xor(bv, s, 16);
    int   oi = __shfl_xor(bi, s, 16);
    if (ov > bv || (ov == bv && oi < bi)) { bv = ov; bi = oi; }
  }
  float p  = expf(l - bv);
  float sm = p;
#pragma unroll
  for (int s = 1; s < 16; s <<= 1) sm += __shfl_xor(sm, s, 16);
  if (e == 0) {
    idx[t0 + q]  = bi;
    gval[t0 + q] = 1.0f / sm;
  }
}

// ---------------- routing scan: capacity-limited slot assignment -------
__global__ void __launch_bounds__(1024)
scan_kernel(const int* __restrict__ idx, int* __restrict__ s2t) {
  const int tid = threadIdx.x;
#pragma unroll
  for (int k = 0; k < 8; ++k) s2t[tid + k * 1024] = -1;
  __shared__ int base[16];
  __shared__ int wavecnt[16][16];
  if (tid < 16) base[tid] = 0;
  __syncthreads();
  const int wid = tid >> 6, lane = tid & 63;
  const unsigned long long ltmask = (1ull << lane) - 1ull;
  for (int c = 0; c < 8; ++c) {
    const int t = c * 1024 + tid;
    const int e = idx[t];
    int rank = 0;
#pragma unroll
    for (int ee = 0; ee < 16; ++ee) {
      unsigned long long m = __ballot(e == ee);
      if (lane == 0) wavecnt[wid][ee] = __popcll(m);
      if (ee == e) rank = __popcll(m & ltmask);
    }
    __syncthreads();
    if (tid < 16) {
      int s = base[tid];
#pragma unroll
      for (int w = 0; w < 16; ++w) { int cc = wavecnt[w][tid]; wavecnt[w][tid] = s; s += cc; }
      base[tid] = s;
    }
    __syncthreads();
    const int loc = wavecnt[wid][e] + rank;
    if (loc < CAP) s2t[e * CAP + loc] = t;
    __syncthreads();
  }
}

// H2 layout: [e][kt(64)][kg(8)][row(512)][8 bf16]; per-expert 4 MB.

// ---------------- GEMM1: H2[e] = relu(gather(Xb)[e] @ w1[e]) -----------
// 128x128, BK=64, 4 waves. A via gload_lds (gathered rows), B reg-split.
#define G1_GX 4
#define G1_GY 32
#define G1_GZ 16
__global__ void __launch_bounds__(256, 2)
gemm1_kernel(const unsigned short* __restrict__ Xb, const float* __restrict__ W1,
             const int* __restrict__ s2t, unsigned short* __restrict__ H2) {
  constexpr int NT = DM / 64;  // 16
  __shared__ __align__(16) char lds[2][32768];

  const int tid = threadIdx.x;
  const int lane = tid & 63, wid = tid >> 6;
  const int wr = wid >> 1, wc = wid & 1;
  const int ln15 = lane & 15, l16 = lane >> 4;

  int flat = blockIdx.x + G1_GX * (blockIdx.y + G1_GY * blockIdx.z);
  flat = (flat & 7) * (G1_GX * G1_GY * G1_GZ / 8) + (flat >> 3);
  const int bx = flat % G1_GX;
  const int by = (flat / G1_GX) % G1_GY;
  const int e  = flat / (G1_GX * G1_GY);
  const int m0 = bx * 128, n0 = by * 128;

  // A: gathered rows, per-lane global addresses
  int tk0 = s2t[e * CAP + m0 + lane];
  int tk1 = s2t[e * CAP + m0 + 64 + lane];
  const char* const a0 = (const char*)Xb + (size_t)(tk0 < 0 ? 0 : tk0) * 2048;
  const char* const a1 = (const char*)Xb + (size_t)(tk1 < 0 ? 0 : tk1) * 2048;

  // B staging: 4 cols c0.., k-rows kgB*8..+8
  const int c0  = (tid & 31) * 4;
  const int kgB = tid >> 5;
  const float* const bsrc = W1 + (size_t)e * DM * NF + (size_t)(kgB * 8) * NF + n0 + c0;

  int bwoff[4], aoff[4], boff[4];
#pragma unroll
  for (int cc = 0; cc < 4; ++cc) bwoff[cc] = 16384 + (kgB * 128 + pcol(c0 + cc)) * 16;
#pragma unroll
  for (int mi = 0; mi < 4; ++mi) aoff[mi] = l16 * 2048 + (wr * 64 + mi * 16 + ln15) * 16;
#pragma unroll
  for (int ni = 0; ni < 4; ++ni) boff[ni] = 16384 + l16 * 2048 + pcol(wc * 64 + ni * 16 + ln15) * 16;

  f32x4 acc[4][4];
#pragma unroll
  for (int mi = 0; mi < 4; ++mi)
#pragma unroll
    for (int ni = 0; ni < 4; ++ni) acc[mi][ni] = f32x4{0.f, 0.f, 0.f, 0.f};

  float4 breg[8];

  auto GLOADA = [&](char* buf, int kt) {
    const int kb = kt * 128 + wid * 32;   // this wave's 2 k-slices (16B each)
    gload_lds16(a0 + kb,      buf + (wid * 4 + 0) * 1024);
    gload_lds16(a1 + kb,      buf + (wid * 4 + 1) * 1024);
    gload_lds16(a0 + kb + 16, buf + (wid * 4 + 2) * 1024);
    gload_lds16(a1 + kb + 16, buf + (wid * 4 + 3) * 1024);
  };
  auto LOADB = [&](int kt) {
    const float* bp = bsrc + (size_t)kt * 64 * NF;
#pragma unroll
    for (int r = 0; r < 8; ++r) breg[r] = *(const float4*)(bp + (size_t)r * NF);
  };
  auto WRITEB = [&](char* buf) {
    const float* br = (const float*)breg;
#pragma unroll
    for (int h = 0; h < 2; ++h)
#pragma unroll
      for (int cc = 0; cc < 4; ++cc)
        *(uint2*)(buf + bwoff[cc] + h * 8) =
            make_uint2(pk2(br[(h * 4 + 0) * 4 + cc], br[(h * 4 + 1) * 4 + cc]),
                       pk2(br[(h * 4 + 2) * 4 + cc], br[(h * 4 + 3) * 4 + cc]));
  };
  auto COMPUTE = [&](const char* buf) {
#pragma unroll
    for (int kk = 0; kk < 2; ++kk) {
      bf16x8 af[4], bf[4];
#pragma unroll
      for (int mi = 0; mi < 4; ++mi)
        af[mi] = *(const bf16x8*)(buf + kk * 8192 + aoff[mi]);
#pragma unroll
      for (int ni = 0; ni < 4; ++ni)
        bf[ni] = *(const bf16x8*)(buf + kk * 8192 + boff[ni]);
#pragma unroll
      for (int mi = 0; mi < 4; ++mi)
#pragma unroll
        for (int ni = 0; ni < 4; ++ni)
          acc[mi][ni] = __builtin_amdgcn_mfma_f32_16x16x32_bf16(af[mi], bf[ni], acc[mi][ni], 0, 0, 0);
    }
  };

  GLOADA(lds[0], 0); LOADB(0); WRITEB(lds[0]);
  __syncthreads();
  for (int kt = 0; kt < NT; kt += 2) {
    GLOADA(lds[1], kt + 1); LOADB(kt + 1);
    COMPUTE(lds[0]);
    WRITEB(lds[1]);
    __syncthreads();
    if (kt + 2 < NT) { GLOADA(lds[0], kt + 2); LOADB(kt + 2); }
    COMPUTE(lds[1]);
    if (kt + 2 < NT) WRITEB(lds[0]);
    __syncthreads();
  }

  // ---- epilogue: relu, LDS transpose to H2-image, contiguous stores ----
  char* img = lds[0];
#pragma unroll
  for (int mi = 0; mi < 4; ++mi) {
#pragma unroll
    for (int ni = 0; ni < 4; ++ni) {
      const int colL = wc * 64 + ni * 16 + ln15;
      const int base = ((colL >> 6) * 8 + ((colL >> 3) & 7)) * 2048 + (colL & 7) * 2;
#pragma unroll
      for (int j = 0; j < 4; ++j) {
        const int rowL = wr * 64 + mi * 16 + l16 * 4 + j;
        float v = acc[mi][ni][j];
        v = v > 0.f ? v : 0.f;
        *(unsigned short*)(img + base + rowL * 16) = f2bf(v);
      }
    }
  }
  __syncthreads();
  const char* src = img + tid * 128;
  const size_t g = (size_t)e * 4194304 + (size_t)(n0 >> 6) * 65536 +
                   (size_t)(tid >> 7) * 65536 + (size_t)((tid >> 4) & 7) * 8192 +
                   (size_t)(m0 + (tid & 15) * 8) * 16;
  char* dst = (char*)H2 + g;
#pragma unroll
  for (int u = 0; u < 8; ++u)
    *(uint4*)(dst + u * 16) = *(const uint4*)(src + u * 16);
}

// ---------------- GEMM2: out[tok] = (H2[e] @ w2[e]) * gate -------------
#define G2_GX 4
#define G2_GY 8
#define G2_GZ 16
__global__ void __launch_bounds__(256, 2)
gemm2_kernel(const unsigned short* __restrict__ H2, const float* __restrict__ W2,
             const int* __restrict__ s2t, const float* __restrict__ gval,
             float* __restrict__ Out) {
  constexpr int NT = NF / 64;  // 64
  __shared__ __align__(16) char lds[2][32768];

  const int tid = threadIdx.x;
  const int lane = tid & 63, wid = tid >> 6;
  const int wr = wid >> 1, wc = wid & 1;
  const int ln15 = lane & 15, l16 = lane >> 4;

  int flat = blockIdx.x + G2_GX * (blockIdx.y + G2_GY * blockIdx.z);
  flat = (flat & 7) * (G2_GX * G2_GY * G2_GZ / 8) + (flat >> 3);
  const int bx = flat % G2_GX;
  const int by = (flat / G2_GX) % G2_GY;
  const int e  = flat / (G2_GX * G2_GY);
  const int m0 = bx * 128, n0 = by * 128;

  const char* const Hex = (const char*)H2 + (size_t)e * 4194304 + (size_t)m0 * 16;
  const int c0  = (tid & 31) * 4;
  const int kgB = tid >> 5;
  const float* const bsrc = W2 + (size_t)e * NF * DM + (size_t)(kgB * 8) * DM + n0 + c0;

  int bwoff[4], aoff[4], boff[4];
#pragma unroll
  for (int cc = 0; cc < 4; ++cc) bwoff[cc] = 16384 + (kgB * 128 + pcol(c0 + cc)) * 16;
#pragma unroll
  for (int mi = 0; mi < 4; ++mi) aoff[mi] = l16 * 2048 + (wr * 64 + mi * 16 + ln15) * 16;
#pragma unroll
  for (int ni = 0; ni < 4; ++ni) boff[ni] = 16384 + l16 * 2048 + pcol(wc * 64 + ni * 16 + ln15) * 16;

  f32x4 acc[4][4];
#pragma unroll
  for (int mi = 0; mi < 4; ++mi)
#pragma unroll
    for (int ni = 0; ni < 4; ++ni) acc[mi][ni] = f32x4{0.f, 0.f, 0.f, 0.f};

  float4 breg[8];

  auto GLOADA = [&](char* buf, int kt) {
#pragma unroll
    for (int i = 0; i < 4; ++i) {
      const int q = i * 4 + wid;
      const char* gp = Hex + (size_t)kt * 65536 + (size_t)(q >> 1) * 8192 +
                       (size_t)((q & 1) * 64 + lane) * 16;
      gload_lds16(gp, buf + q * 1024);
    }
  };
  auto LOADB = [&](int kt) {
    const float* bp = bsrc + (size_t)kt * 64 * DM;
#pragma unroll
    for (int r = 0; r < 8; ++r) breg[r] = *(const float4*)(bp + (size_t)r * DM);
  };
  auto WRITEB = [&](char* buf) {
    const float* br = (const float*)breg;
#pragma unroll
    for (int h = 0; h < 2; ++h)
#pragma unroll
      for (int cc = 0; cc < 4; ++cc)
        *(uint2*)(buf + bwoff[cc] + h * 8) =
            make_uint2(pk2(br[(h * 4 + 0) * 4 + cc], br[(h * 4 + 1) * 4 + cc]),
                       pk2(br[(h * 4 + 2) * 4 + cc], br[(h * 4 + 3) * 4 + cc]));
  };
  auto COMPUTE = [&](const char* buf) {
#pragma unroll
    for (int kk = 0; kk < 2; ++kk) {
      bf16x8 af[4], bf[4];
#pragma unroll
      for (int mi = 0; mi < 4; ++mi)
        af[mi] = *(const bf16x8*)(buf + kk * 8192 + aoff[mi]);
#pragma unroll
      for (int ni = 0; ni < 4; ++ni)
        bf[ni] = *(const bf16x8*)(buf + kk * 8192 + boff[ni]);
#pragma unroll
      for (int mi = 0; mi < 4; ++mi)
#pragma unroll
        for (int ni = 0; ni < 4; ++ni)
          acc[mi][ni] = __builtin_amdgcn_mfma_f32_16x16x32_bf16(af[mi], bf[ni], acc[mi][ni], 0, 0, 0);
    }
  };

  GLOADA(lds[0], 0); LOADB(0); WRITEB(lds[0]);
  __syncthreads();
  for (int kt = 0; kt < NT; kt += 2) {
    GLOADA(lds[1], kt + 1); LOADB(kt + 1);
    COMPUTE(lds[0]);
    WRITEB(lds[1]);
    __syncthreads();
    if (kt + 2 < NT) { GLOADA(lds[0], kt + 2); LOADB(kt + 2); }
    COMPUTE(lds[1]);
    if (kt + 2 < NT) WRITEB(lds[0]);
    __syncthreads();
  }

#pragma unroll
  for (int mi = 0; mi < 4; ++mi) {
#pragma unroll
    for (int ni = 0; ni < 4; ++ni) {
      const int col = n0 + wc * 64 + ni * 16 + ln15;
#pragma unroll
      for (int j = 0; j < 4; ++j) {
        const int row = m0 + wr * 64 + mi * 16 + l16 * 4 + j;
        const int tk = s2t[e * CAP + row];
        if (tk >= 0)
          Out[(size_t)tk * DM + col] = acc[mi][ni][j] * gval[tk];
      }
    }
  }
}

// ----------------------------- launcher --------------------------------
extern "C" void kernel_launch(void* const* d_in, const int* in_sizes, int n_in,
                              void* d_out, int out_size, void* d_ws, size_t ws_size,
                              hipStream_t stream) {
  (void)in_sizes; (void)n_in; (void)ws_size;
  const float* X  = (const float*)d_in[0];
  const float* Wg = (const float*)d_in[1];
  const float* W1 = (const float*)d_in[2];
  const float* W2 = (const float*)d_in[3];
  float* Out = (float*)d_out;

  char* ws = (char*)d_ws;
  int*   s2t  = (int*)ws;                            // 32 KB
  int*   idx  = (int*)(ws + 32768);
  float* gval = (float*)(ws + 65536);
  unsigned short* Xb = (unsigned short*)(ws + 98304);            // 16 MB
  unsigned short* H2 = (unsigned short*)(ws + 98304 + 16777216); // 64 MB

  hipMemsetAsync(d_out, 0, (size_t)out_size * sizeof(float), stream);
  cvt_kernel<<<2048, 256, 0, stream>>>(X, Xb);
  gate_kernel<<<S_TOK / 16, 256, 0, stream>>>(X, Wg, idx, gval);
  scan_kernel<<<1, 1024, 0, stream>>>(idx, s2t);
  gemm1_kernel<<<dim3(G1_GX, G1_GY, G1_GZ), 256, 0, stream>>>(Xb, W1, s2t, H2);
  gemm2_kernel<<<dim3(G2_GX, G2_GY, G2_GZ), 256, 0, stream>>>(H2, W2, s2t, gval, Out);
}

// Round 6
// 305.182 us; speedup vs baseline: 1.9902x; 1.2178x over previous
//
#include <hip/hip_runtime.h>
#include <cstdint>
#include <cstddef>

#define S_TOK 8192
#define DM    1024
#define NE    16
#define NF    4096
#define CAP   512

typedef __attribute__((ext_vector_type(8))) short bf16x8;
typedef __attribute__((ext_vector_type(4))) float f32x4;

__device__ __forceinline__ unsigned short f2bf(float f) {
  __bf16 b = (__bf16)f;
  return __builtin_bit_cast(unsigned short, b);
}
__device__ __forceinline__ unsigned pk2(float a, float b) {
  return (unsigned)f2bf(a) | ((unsigned)f2bf(b) << 16);
}
// bank-spread for the B [kg][col][16B] LDS layout
__device__ __forceinline__ int pcol(int c) { return c ^ ((c >> 3) & 7); }

__device__ __forceinline__ void gload_lds16(const void* g, void* l) {
  __builtin_amdgcn_global_load_lds(
      (const __attribute__((address_space(1))) void*)g,
      (__attribute__((address_space(3))) void*)l, 16, 0, 0);
}

// ---------------- X fp32 -> bf16 convert (one pass) --------------------
__global__ void __launch_bounds__(256)
cvt_kernel(const float* __restrict__ X, unsigned short* __restrict__ Xb) {
  const int t = blockIdx.x * 256 + threadIdx.x;   // 16 elems per thread
  const float4* src = (const float4*)X + (size_t)t * 4;
  float4 v0 = src[0], v1 = src[1], v2 = src[2], v3 = src[3];
  uint4 o0 = make_uint4(pk2(v0.x, v0.y), pk2(v0.z, v0.w),
                        pk2(v1.x, v1.y), pk2(v1.z, v1.w));
  uint4 o1 = make_uint4(pk2(v2.x, v2.y), pk2(v2.z, v2.w),
                        pk2(v3.x, v3.y), pk2(v3.z, v3.w));
  uint4* dst = (uint4*)Xb + (size_t)t * 2;
  dst[0] = o0; dst[1] = o1;
}

// ---------------- gating: logits fp32, softmax, argmax -----------------
__global__ void __launch_bounds__(256)
gate_kernel(const float* __restrict__ X, const float* __restrict__ Wg,
            int* __restrict__ idx, float* __restrict__ gval) {
  const int tid  = threadIdx.x;
  const int lane = tid & 63;
  const int wid  = tid >> 6;
  const int e = lane & 15, q = lane >> 4;
  const int t0 = blockIdx.x * 16 + wid * 4;
  const int mbase = q * 256;

  const float* xp0 = X + (size_t)(t0 + 0) * DM + mbase;
  const float* xp1 = X + (size_t)(t0 + 1) * DM + mbase;
  const float* xp2 = X + (size_t)(t0 + 2) * DM + mbase;
  const float* xp3 = X + (size_t)(t0 + 3) * DM + mbase;
  const float* wp  = Wg + (size_t)mbase * NE + e;

  float a0 = 0.f, a1 = 0.f, a2 = 0.f, a3 = 0.f;
#pragma unroll 4
  for (int i = 0; i < 64; ++i) {
    float4 x0 = *(const float4*)(xp0 + i * 4);
    float4 x1 = *(const float4*)(xp1 + i * 4);
    float4 x2 = *(const float4*)(xp2 + i * 4);
    float4 x3 = *(const float4*)(xp3 + i * 4);
    float w0 = wp[(i * 4 + 0) * NE];
    float w1 = wp[(i * 4 + 1) * NE];
    float w2 = wp[(i * 4 + 2) * NE];
    float w3 = wp[(i * 4 + 3) * NE];
    a0 = fmaf(x0.x, w0, fmaf(x0.y, w1, fmaf(x0.z, w2, fmaf(x0.w, w3, a0))));
    a1 = fmaf(x1.x, w0, fmaf(x1.y, w1, fmaf(x1.z, w2, fmaf(x1.w, w3, a1))));
    a2 = fmaf(x2.x, w0, fmaf(x2.y, w1, fmaf(x2.z, w2, fmaf(x2.w, w3, a2))));
    a3 = fmaf(x3.x, w0, fmaf(x3.y, w1, fmaf(x3.z, w2, fmaf(x3.w, w3, a3))));
  }
#pragma unroll
  for (int s = 16; s < 64; s <<= 1) {
    a0 += __shfl_xor(a0, s, 64);
    a1 += __shfl_xor(a1, s, 64);
    a2 += __shfl_xor(a2, s, 64);
    a3 += __shfl_xor(a3, s, 64);
  }
  float l = (q == 0) ? a0 : (q == 1) ? a1 : (q == 2) ? a2 : a3;
  float bv = l; int bi = e;
#pragma unroll
  for (int s = 1; s < 16; s <<= 1) {
    float ov = __shfl_xor(bv, s, 16);
    int   oi = __shfl_xor(bi, s, 16);
    if (ov > bv || (ov == bv && oi < bi)) { bv = ov; bi = oi; }
  }
  float p  = expf(l - bv);
  float sm = p;
#pragma unroll
  for (int s = 1; s < 16; s <<= 1) sm += __shfl_xor(sm, s, 16);
  if (e == 0) {
    idx[t0 + q]  = bi;
    gval[t0 + q] = 1.0f / sm;
  }
}

// ---------------- routing scan: capacity-limited slot assignment -------
__global__ void __launch_bounds__(1024)
scan_kernel(const int* __restrict__ idx, int* __restrict__ s2t) {
  const int tid = threadIdx.x;
#pragma unroll
  for (int k = 0; k < 8; ++k) s2t[tid + k * 1024] = -1;
  __shared__ int base[16];
  __shared__ int wavecnt[16][16];
  if (tid < 16) base[tid] = 0;
  __syncthreads();
  const int wid = tid >> 6, lane = tid & 63;
  const unsigned long long ltmask = (1ull << lane) - 1ull;
  for (int c = 0; c < 8; ++c) {
    const int t = c * 1024 + tid;
    const int e = idx[t];
    int rank = 0;
#pragma unroll
    for (int ee = 0; ee < 16; ++ee) {
      unsigned long long m = __ballot(e == ee);
      if (lane == 0) wavecnt[wid][ee] = __popcll(m);
      if (ee == e) rank = __popcll(m & ltmask);
    }
    __syncthreads();
    if (tid < 16) {
      int s = base[tid];
#pragma unroll
      for (int w = 0; w < 16; ++w) { int cc = wavecnt[w][tid]; wavecnt[w][tid] = s; s += cc; }
      base[tid] = s;
    }
    __syncthreads();
    const int loc = wavecnt[wid][e] + rank;
    if (loc < CAP) s2t[e * CAP + loc] = t;
    __syncthreads();
  }
}

// H2 layout: [e][kt(64)][kg(8)][row(512)][8 bf16]; per-expert 4 MB.

// =======================================================================
// GEMM skeleton: 256(M)x128(N) tile, BK=64, 512 thr (8 waves, 4Mx2N).
// A: triple-buffered LDS via global_load_lds (depth-2 prefetch),
//    rotating INTEGER offsets (pointer arrays of LDS don't compile).
// B: double-buffered LDS, reg-staged fp32->bf16 (loads 1 iter ahead).
// One raw s_barrier per iter with COUNTED s_waitcnt vmcnt(8) -- the 8
// loads for tile kt+2 stay in flight across the barrier (T3+T4).
// LDS: A 3x32KB @0, B 2x16KB @98304 = 128 KB.
// =======================================================================

// ---------------- GEMM1: H2[e] = relu(gather(Xb)[e] @ w1[e]) -----------
#define G1_BX 2
#define G1_BY 32
#define G1_BZ 16
__global__ void __launch_bounds__(512, 2)
gemm1_kernel(const unsigned short* __restrict__ Xb, const float* __restrict__ W1,
             const int* __restrict__ s2t, unsigned short* __restrict__ H2) {
  constexpr int NT = DM / 64;  // 16
  __shared__ __align__(16) char lds[131072];

  const int tid = threadIdx.x;
  const int lane = tid & 63, wid = tid >> 6;
  const int wr = wid >> 1, wc = wid & 1;
  const int ln15 = lane & 15, l16 = lane >> 4;

  int flat = blockIdx.x + G1_BX * (blockIdx.y + G1_BY * blockIdx.z);
  flat = (flat & 7) * (G1_BX * G1_BY * G1_BZ / 8) + (flat >> 3);
  const int bx = flat % G1_BX;
  const int by = (flat / G1_BX) % G1_BY;
  const int e  = flat / (G1_BX * G1_BY);
  const int m0 = bx * 256, n0 = by * 128;

  char* const Bb0 = lds + 98304;
  char* const Bb1 = lds + 98304 + 16384;

  // A gather: wave covers rows rb*64+lane (rb = wid>>1), kg = (wid&1)*4+j
  const int rb = wid >> 1;
  const int tok = s2t[e * CAP + m0 + rb * 64 + lane];
  const char* const asrc = (const char*)Xb + (size_t)(tok < 0 ? 0 : tok) * 2048;
  const int kgw = (wid & 1) * 4;
  const int adst = kgw * 4096 + rb * 1024;

  // B: cols c0..c0+3, k-rows 4*kq..4*kq+3
  const int c0 = (tid & 31) * 4;
  const int kq = tid >> 5;
  const float* const bsrc = W1 + (size_t)e * DM * NF + (size_t)(kq * 4) * NF + n0 + c0;
  const int kgb = kq >> 1, hb = kq & 1;
  int bwoff[4];
#pragma unroll
  for (int cc = 0; cc < 4; ++cc) bwoff[cc] = kgb * 2048 + pcol(c0 + cc) * 16 + hb * 8;

  int aoff[4], boff[4];
#pragma unroll
  for (int mi = 0; mi < 4; ++mi) aoff[mi] = l16 * 4096 + (wr * 64 + mi * 16 + ln15) * 16;
#pragma unroll
  for (int ni = 0; ni < 4; ++ni) boff[ni] = l16 * 2048 + pcol(wc * 64 + ni * 16 + ln15) * 16;

  f32x4 acc[4][4];
#pragma unroll
  for (int mi = 0; mi < 4; ++mi)
#pragma unroll
    for (int ni = 0; ni < 4; ++ni) acc[mi][ni] = f32x4{0.f, 0.f, 0.f, 0.f};

  float4 breg[4];

  auto ISSUE_B = [&](int kt) {
    const float* bp = bsrc + (size_t)kt * 64 * NF;
#pragma unroll
    for (int r = 0; r < 4; ++r) breg[r] = *(const float4*)(bp + (size_t)r * NF);
  };
  auto ISSUE_A = [&](int Aoff, int kt) {
#pragma unroll
    for (int j = 0; j < 4; ++j)
      gload_lds16(asrc + kt * 128 + (kgw + j) * 16, lds + Aoff + adst + j * 4096);
  };
  auto WRITEB = [&](char* Bbuf) {
    const float* f = (const float*)breg;
#pragma unroll
    for (int cc = 0; cc < 4; ++cc)
      *(uint2*)(Bbuf + bwoff[cc]) =
          make_uint2(pk2(f[0 + cc], f[4 + cc]), pk2(f[8 + cc], f[12 + cc]));
  };
  auto COMPUTE = [&](int Aoff, const char* Bbuf) {
#pragma unroll
    for (int kk = 0; kk < 2; ++kk) {
      bf16x8 af[4], bf[4];
#pragma unroll
      for (int mi = 0; mi < 4; ++mi)
        af[mi] = *(const bf16x8*)(lds + Aoff + kk * 16384 + aoff[mi]);
#pragma unroll
      for (int ni = 0; ni < 4; ++ni)
        bf[ni] = *(const bf16x8*)(Bbuf + kk * 8192 + boff[ni]);
#pragma unroll
      for (int mi = 0; mi < 4; ++mi)
#pragma unroll
        for (int ni = 0; ni < 4; ++ni)
          acc[mi][ni] = __builtin_amdgcn_mfma_f32_16x16x32_bf16(af[mi], bf[ni], acc[mi][ni], 0, 0, 0);
    }
  };

  // prologue
  ISSUE_B(0); ISSUE_A(0, 0);
  WRITEB(Bb0);                       // compiler inserts exact vmcnt for breg
  ISSUE_B(1); ISSUE_A(32768, 1);
  asm volatile("s_waitcnt vmcnt(8) lgkmcnt(0)" ::: "memory");
  __builtin_amdgcn_s_barrier();

  int aCur = 0, aNxt = 32768, aNx2 = 65536;
  for (int kt = 0; kt < NT; ++kt) {
    WRITEB((kt & 1) ? Bb0 : Bb1);    // B(kt+1) -> Bb[(kt+1)&1]
    const int tl = (kt + 2 < NT) ? kt + 2 : NT - 1;
    ISSUE_B(tl);
    ISSUE_A(aNx2, tl);
    COMPUTE(aCur, (kt & 1) ? Bb1 : Bb0);
    asm volatile("s_waitcnt vmcnt(8) lgkmcnt(0)" ::: "memory");
    __builtin_amdgcn_s_barrier();
    const int t = aCur; aCur = aNxt; aNxt = aNx2; aNx2 = t;
  }
  asm volatile("s_waitcnt vmcnt(0)" ::: "memory");
  __builtin_amdgcn_s_barrier();

  // ---- epilogue: relu, LDS transpose to H2-image (64KB @ lds+0) -------
  char* img = lds;
#pragma unroll
  for (int mi = 0; mi < 4; ++mi) {
#pragma unroll
    for (int ni = 0; ni < 4; ++ni) {
      const int colL = wc * 64 + ni * 16 + ln15;
      const int basei = (colL >> 6) * 32768 + ((colL >> 3) & 7) * 4096 + (colL & 7) * 2;
#pragma unroll
      for (int j = 0; j < 4; ++j) {
        const int rowL = wr * 64 + mi * 16 + l16 * 4 + j;
        float v = acc[mi][ni][j];
        v = v > 0.f ? v : 0.f;
        *(unsigned short*)(img + basei + rowL * 16) = f2bf(v);
      }
    }
  }
  __syncthreads();
  const char* src = img + tid * 128;
  char* dst = (char*)H2 + (size_t)e * 4194304 +
              (size_t)((n0 >> 6) + (tid >> 8)) * 65536 +
              (size_t)((tid >> 5) & 7) * 8192 +
              (size_t)(m0 + (tid & 31) * 8) * 16;
#pragma unroll
  for (int u = 0; u < 8; ++u)
    *(uint4*)(dst + u * 16) = *(const uint4*)(src + u * 16);
}

// ---------------- GEMM2: out[tok] = (H2[e] @ w2[e]) * gate -------------
#define G2_BX 2
#define G2_BY 8
#define G2_BZ 16
__global__ void __launch_bounds__(512, 2)
gemm2_kernel(const unsigned short* __restrict__ H2, const float* __restrict__ W2,
             const int* __restrict__ s2t, const float* __restrict__ gval,
             float* __restrict__ Out) {
  constexpr int NT = NF / 64;  // 64
  __shared__ __align__(16) char lds[131072];

  const int tid = threadIdx.x;
  const int lane = tid & 63, wid = tid >> 6;
  const int wr = wid >> 1, wc = wid & 1;
  const int ln15 = lane & 15, l16 = lane >> 4;

  int flat = blockIdx.x + G2_BX * (blockIdx.y + G2_BY * blockIdx.z);
  flat = (flat & 7) * (G2_BX * G2_BY * G2_BZ / 8) + (flat >> 3);
  const int bx = flat % G2_BX;
  const int by = (flat / G2_BX) % G2_BY;
  const int e  = flat / (G2_BX * G2_BY);
  const int m0 = bx * 256, n0 = by * 128;

  char* const Bb0 = lds + 98304;
  char* const Bb1 = lds + 98304 + 16384;

  const int rb = wid >> 1;
  const int kgw = (wid & 1) * 4;
  const int adst = kgw * 4096 + rb * 1024;
  const char* const Hex = (const char*)H2 + (size_t)e * 4194304 + (size_t)m0 * 16 +
                          (size_t)(rb * 64 + lane) * 16;

  const int c0 = (tid & 31) * 4;
  const int kq = tid >> 5;
  const float* const bsrc = W2 + (size_t)e * NF * DM + (size_t)(kq * 4) * DM + n0 + c0;
  const int kgb = kq >> 1, hb = kq & 1;
  int bwoff[4];
#pragma unroll
  for (int cc = 0; cc < 4; ++cc) bwoff[cc] = kgb * 2048 + pcol(c0 + cc) * 16 + hb * 8;

  int aoff[4], boff[4];
#pragma unroll
  for (int mi = 0; mi < 4; ++mi) aoff[mi] = l16 * 4096 + (wr * 64 + mi * 16 + ln15) * 16;
#pragma unroll
  for (int ni = 0; ni < 4; ++ni) boff[ni] = l16 * 2048 + pcol(wc * 64 + ni * 16 + ln15) * 16;

  f32x4 acc[4][4];
#pragma unroll
  for (int mi = 0; mi < 4; ++mi)
#pragma unroll
    for (int ni = 0; ni < 4; ++ni) acc[mi][ni] = f32x4{0.f, 0.f, 0.f, 0.f};

  float4 breg[4];

  auto ISSUE_B = [&](int kt) {
    const float* bp = bsrc + (size_t)kt * 64 * DM;
#pragma unroll
    for (int r = 0; r < 4; ++r) breg[r] = *(const float4*)(bp + (size_t)r * DM);
  };
  auto ISSUE_A = [&](int Aoff, int kt) {
#pragma unroll
    for (int j = 0; j < 4; ++j)
      gload_lds16(Hex + (size_t)kt * 65536 + (size_t)(kgw + j) * 8192,
                  lds + Aoff + adst + j * 4096);
  };
  auto WRITEB = [&](char* Bbuf) {
    const float* f = (const float*)breg;
#pragma unroll
    for (int cc = 0; cc < 4; ++cc)
      *(uint2*)(Bbuf + bwoff[cc]) =
          make_uint2(pk2(f[0 + cc], f[4 + cc]), pk2(f[8 + cc], f[12 + cc]));
  };
  auto COMPUTE = [&](int Aoff, const char* Bbuf) {
#pragma unroll
    for (int kk = 0; kk < 2; ++kk) {
      bf16x8 af[4], bf[4];
#pragma unroll
      for (int mi = 0; mi < 4; ++mi)
        af[mi] = *(const bf16x8*)(lds + Aoff + kk * 16384 + aoff[mi]);
#pragma unroll
      for (int ni = 0; ni < 4; ++ni)
        bf[ni] = *(const bf16x8*)(Bbuf + kk * 8192 + boff[ni]);
#pragma unroll
      for (int mi = 0; mi < 4; ++mi)
#pragma unroll
        for (int ni = 0; ni < 4; ++ni)
          acc[mi][ni] = __builtin_amdgcn_mfma_f32_16x16x32_bf16(af[mi], bf[ni], acc[mi][ni], 0, 0, 0);
    }
  };

  ISSUE_B(0); ISSUE_A(0, 0);
  WRITEB(Bb0);
  ISSUE_B(1); ISSUE_A(32768, 1);
  asm volatile("s_waitcnt vmcnt(8) lgkmcnt(0)" ::: "memory");
  __builtin_amdgcn_s_barrier();

  int aCur = 0, aNxt = 32768, aNx2 = 65536;
  for (int kt = 0; kt < NT; ++kt) {
    WRITEB((kt & 1) ? Bb0 : Bb1);
    const int tl = (kt + 2 < NT) ? kt + 2 : NT - 1;
    ISSUE_B(tl);
    ISSUE_A(aNx2, tl);
    COMPUTE(aCur, (kt & 1) ? Bb1 : Bb0);
    asm volatile("s_waitcnt vmcnt(8) lgkmcnt(0)" ::: "memory");
    __builtin_amdgcn_s_barrier();
    const int t = aCur; aCur = aNxt; aNxt = aNx2; aNx2 = t;
  }
  asm volatile("s_waitcnt vmcnt(0)" ::: "memory");

#pragma unroll
  for (int mi = 0; mi < 4; ++mi) {
#pragma unroll
    for (int ni = 0; ni < 4; ++ni) {
      const int col = n0 + wc * 64 + ni * 16 + ln15;
#pragma unroll
      for (int j = 0; j < 4; ++j) {
        const int row = m0 + wr * 64 + mi * 16 + l16 * 4 + j;
        const int tk = s2t[e * CAP + row];
        if (tk >= 0)
          Out[(size_t)tk * DM + col] = acc[mi][ni][j] * gval[tk];
      }
    }
  }
}

// ----------------------------- launcher --------------------------------
extern "C" void kernel_launch(void* const* d_in, const int* in_sizes, int n_in,
                              void* d_out, int out_size, void* d_ws, size_t ws_size,
                              hipStream_t stream) {
  (void)in_sizes; (void)n_in; (void)ws_size;
  const float* X  = (const float*)d_in[0];
  const float* Wg = (const float*)d_in[1];
  const float* W1 = (const float*)d_in[2];
  const float* W2 = (const float*)d_in[3];
  float* Out = (float*)d_out;

  char* ws = (char*)d_ws;
  int*   s2t  = (int*)ws;                            // 32 KB
  int*   idx  = (int*)(ws + 32768);
  float* gval = (float*)(ws + 65536);
  unsigned short* Xb = (unsigned short*)(ws + 98304);            // 16 MB
  unsigned short* H2 = (unsigned short*)(ws + 98304 + 16777216); // 64 MB

  (void)hipMemsetAsync(d_out, 0, (size_t)out_size * sizeof(float), stream);
  cvt_kernel<<<2048, 256, 0, stream>>>(X, Xb);
  gate_kernel<<<S_TOK / 16, 256, 0, stream>>>(X, Wg, idx, gval);
  scan_kernel<<<1, 1024, 0, stream>>>(idx, s2t);
  gemm1_kernel<<<dim3(G1_BX, G1_BY, G1_BZ), 512, 0, stream>>>(Xb, W1, s2t, H2);
  gemm2_kernel<<<dim3(G2_BX, G2_BY, G2_BZ), 512, 0, stream>>>(H2, W2, s2t, gval, Out);
}

// Round 7
// 280.655 us; speedup vs baseline: 2.1641x; 1.0874x over previous
//
#include <hip/hip_runtime.h>
#include <cstdint>
#include <cstddef>

#define S_TOK 8192
#define DM    1024
#define NE    16
#define NF    4096
#define CAP   512

typedef __attribute__((ext_vector_type(8))) short bf16x8;
typedef __attribute__((ext_vector_type(4))) float f32x4;

__device__ __forceinline__ unsigned short f2bf(float f) {
  __bf16 b = (__bf16)f;
  return __builtin_bit_cast(unsigned short, b);
}
__device__ __forceinline__ unsigned pk2(float a, float b) {
  return (unsigned)f2bf(a) | ((unsigned)f2bf(b) << 16);
}
// bank-spread for the B [kg][col][16B] LDS layout
__device__ __forceinline__ int pcol(int c) { return c ^ ((c >> 3) & 7); }

__device__ __forceinline__ void gload_lds16(const void* g, void* l) {
  __builtin_amdgcn_global_load_lds(
      (const __attribute__((address_space(1))) void*)g,
      (__attribute__((address_space(3))) void*)l, 16, 0, 0);
}

// ---------------- gating: logits fp32, softmax, argmax -----------------
__global__ void __launch_bounds__(256)
gate_kernel(const float* __restrict__ X, const float* __restrict__ Wg,
            int* __restrict__ idx, float* __restrict__ gval) {
  const int tid  = threadIdx.x;
  const int lane = tid & 63;
  const int wid  = tid >> 6;
  const int e = lane & 15, q = lane >> 4;
  const int t0 = blockIdx.x * 16 + wid * 4;
  const int mbase = q * 256;

  const float* xp0 = X + (size_t)(t0 + 0) * DM + mbase;
  const float* xp1 = X + (size_t)(t0 + 1) * DM + mbase;
  const float* xp2 = X + (size_t)(t0 + 2) * DM + mbase;
  const float* xp3 = X + (size_t)(t0 + 3) * DM + mbase;
  const float* wp  = Wg + (size_t)mbase * NE + e;

  float a0 = 0.f, a1 = 0.f, a2 = 0.f, a3 = 0.f;
#pragma unroll 4
  for (int i = 0; i < 64; ++i) {
    float4 x0 = *(const float4*)(xp0 + i * 4);
    float4 x1 = *(const float4*)(xp1 + i * 4);
    float4 x2 = *(const float4*)(xp2 + i * 4);
    float4 x3 = *(const float4*)(xp3 + i * 4);
    float w0 = wp[(i * 4 + 0) * NE];
    float w1 = wp[(i * 4 + 1) * NE];
    float w2 = wp[(i * 4 + 2) * NE];
    float w3 = wp[(i * 4 + 3) * NE];
    a0 = fmaf(x0.x, w0, fmaf(x0.y, w1, fmaf(x0.z, w2, fmaf(x0.w, w3, a0))));
    a1 = fmaf(x1.x, w0, fmaf(x1.y, w1, fmaf(x1.z, w2, fmaf(x1.w, w3, a1))));
    a2 = fmaf(x2.x, w0, fmaf(x2.y, w1, fmaf(x2.z, w2, fmaf(x2.w, w3, a2))));
    a3 = fmaf(x3.x, w0, fmaf(x3.y, w1, fmaf(x3.z, w2, fmaf(x3.w, w3, a3))));
  }
#pragma unroll
  for (int s = 16; s < 64; s <<= 1) {
    a0 += __shfl_xor(a0, s, 64);
    a1 += __shfl_xor(a1, s, 64);
    a2 += __shfl_xor(a2, s, 64);
    a3 += __shfl_xor(a3, s, 64);
  }
  float l = (q == 0) ? a0 : (q == 1) ? a1 : (q == 2) ? a2 : a3;
  float bv = l; int bi = e;
#pragma unroll
  for (int s = 1; s < 16; s <<= 1) {
    float ov = __shfl_xor(bv, s, 16);
    int   oi = __shfl_xor(bi, s, 16);
    if (ov > bv || (ov == bv && oi < bi)) { bv = ov; bi = oi; }
  }
  float p  = expf(l - bv);
  float sm = p;
#pragma unroll
  for (int s = 1; s < 16; s <<= 1) sm += __shfl_xor(sm, s, 16);
  if (e == 0) {
    idx[t0 + q]  = bi;
    gval[t0 + q] = 1.0f / sm;
  }
}

// ---------------- routing scan: capacity-limited slot assignment -------
__global__ void __launch_bounds__(1024)
scan_kernel(const int* __restrict__ idx, int* __restrict__ s2t) {
  const int tid = threadIdx.x;
#pragma unroll
  for (int k = 0; k < 8; ++k) s2t[tid + k * 1024] = -1;
  __shared__ int base[16];
  __shared__ int wavecnt[16][16];
  if (tid < 16) base[tid] = 0;
  __syncthreads();
  const int wid = tid >> 6, lane = tid & 63;
  const unsigned long long ltmask = (1ull << lane) - 1ull;
  for (int c = 0; c < 8; ++c) {
    const int t = c * 1024 + tid;
    const int e = idx[t];
    int rank = 0;
#pragma unroll
    for (int ee = 0; ee < 16; ++ee) {
      unsigned long long m = __ballot(e == ee);
      if (lane == 0) wavecnt[wid][ee] = __popcll(m);
      if (ee == e) rank = __popcll(m & ltmask);
    }
    __syncthreads();
    if (tid < 16) {
      int s = base[tid];
#pragma unroll
      for (int w = 0; w < 16; ++w) { int cc = wavecnt[w][tid]; wavecnt[w][tid] = s; s += cc; }
      base[tid] = s;
    }
    __syncthreads();
    const int loc = wavecnt[wid][e] + rank;
    if (loc < CAP) s2t[e * CAP + loc] = t;
    __syncthreads();
  }
}

// ---------------- gather + cvt: X fp32 rows -> blocked gathered bf16 ----
// Xg layout: [e][kt(16)][kg(8)][slot(512)][16B]; 1 MB/expert, 16 MB.
__global__ void __launch_bounds__(256)
gather_kernel(const float* __restrict__ X, const int* __restrict__ s2t,
              unsigned short* __restrict__ Xg) {
  const int tid = threadIdx.x;
  const int d  = tid & 127;           // 8 floats per thread
  const int sl = tid >> 7;            // 0..1
  const int s0 = blockIdx.x * 16;     // 16 slots per block
#pragma unroll 2
  for (int p = 0; p < 8; ++p) {
    const int s = s0 + p * 2 + sl;
    const int tok = s2t[s];
    uint4 w;
    if (tok >= 0) {
      const float* xp = X + (size_t)tok * DM + d * 8;
      float4 v0 = *(const float4*)xp;
      float4 v1 = *(const float4*)(xp + 4);
      w = make_uint4(pk2(v0.x, v0.y), pk2(v0.z, v0.w),
                     pk2(v1.x, v1.y), pk2(v1.z, v1.w));
    } else {
      w = make_uint4(0u, 0u, 0u, 0u);
    }
    char* dst = (char*)Xg + (size_t)(s >> 9) * 1048576 +
                (size_t)(d >> 3) * 65536 + (size_t)(d & 7) * 8192 +
                (size_t)(s & 511) * 16;
    *(uint4*)dst = w;
  }
}

// H2 layout: [e][kt(64)][kg(8)][row(512)][8 bf16]; per-expert 4 MB.

// =======================================================================
// GEMM skeleton: 256(M)x128(N) tile, BK=64, 512 thr (8 waves, 4Mx2N).
// A: triple-buffered LDS via global_load_lds (depth-2 prefetch, fully
//    contiguous blocked source for BOTH gemms now).
// B: double-buffered LDS, reg-staged fp32->bf16 (loads 1 iter ahead).
// One raw s_barrier per iter with COUNTED s_waitcnt vmcnt(8).
// XCD co-location: xcd = flat&7 owns 2 experts; both bx halves of a
// weight strip + all by strips of an expert share that XCD's L2.
// LDS: A 3x32KB @0, B 2x16KB @98304 = 128 KB.
// =======================================================================

// ---------------- GEMM1: H2[e] = relu(Xg[e] @ w1[e]) -------------------
#define G1_BX 2
#define G1_BY 32
#define G1_BZ 16
__global__ void __launch_bounds__(512, 2)
gemm1_kernel(const unsigned short* __restrict__ Xg, const float* __restrict__ W1,
             unsigned short* __restrict__ H2) {
  constexpr int NT = DM / 64;  // 16
  __shared__ __align__(16) char lds[131072];

  const int tid = threadIdx.x;
  const int lane = tid & 63, wid = tid >> 6;
  const int wr = wid >> 1, wc = wid & 1;
  const int ln15 = lane & 15, l16 = lane >> 4;

  const int flat = blockIdx.x + G1_BX * (blockIdx.y + G1_BY * blockIdx.z);
  const int xcd = flat & 7, jj = flat >> 3;      // jj 0..127
  const int e  = xcd * 2 + (jj >> 6);
  const int rr = jj & 63;
  const int by = rr >> 1, bx = rr & 1;
  const int m0 = bx * 256, n0 = by * 128;

  char* const Bb0 = lds + 98304;
  char* const Bb1 = lds + 98304 + 16384;

  // A: blocked gathered source; wave covers rows rb*64+lane, kg kgw..kgw+3
  const int rb = wid >> 1;
  const int kgw = (wid & 1) * 4;
  const int adst = kgw * 4096 + rb * 1024;
  const char* const Xge = (const char*)Xg + (size_t)e * 1048576 +
                          (size_t)(m0 + rb * 64 + lane) * 16;

  // B: cols c0..c0+3, k-rows 4*kq..4*kq+3
  const int c0 = (tid & 31) * 4;
  const int kq = tid >> 5;
  const float* const bsrc = W1 + (size_t)e * DM * NF + (size_t)(kq * 4) * NF + n0 + c0;
  const int kgb = kq >> 1, hb = kq & 1;
  int bwoff[4];
#pragma unroll
  for (int cc = 0; cc < 4; ++cc) bwoff[cc] = kgb * 2048 + pcol(c0 + cc) * 16 + hb * 8;

  int aoff[4], boff[4];
#pragma unroll
  for (int mi = 0; mi < 4; ++mi) aoff[mi] = l16 * 4096 + (wr * 64 + mi * 16 + ln15) * 16;
#pragma unroll
  for (int ni = 0; ni < 4; ++ni) boff[ni] = l16 * 2048 + pcol(wc * 64 + ni * 16 + ln15) * 16;

  f32x4 acc[4][4];
#pragma unroll
  for (int mi = 0; mi < 4; ++mi)
#pragma unroll
    for (int ni = 0; ni < 4; ++ni) acc[mi][ni] = f32x4{0.f, 0.f, 0.f, 0.f};

  float4 breg[4];

  auto ISSUE_B = [&](int kt) {
    const float* bp = bsrc + (size_t)kt * 64 * NF;
#pragma unroll
    for (int r = 0; r < 4; ++r) breg[r] = *(const float4*)(bp + (size_t)r * NF);
  };
  auto ISSUE_A = [&](int Aoff, int kt) {
#pragma unroll
    for (int j = 0; j < 4; ++j)
      gload_lds16(Xge + (size_t)kt * 65536 + (size_t)(kgw + j) * 8192,
                  lds + Aoff + adst + j * 4096);
  };
  auto WRITEB = [&](char* Bbuf) {
    const float* f = (const float*)breg;
#pragma unroll
    for (int cc = 0; cc < 4; ++cc)
      *(uint2*)(Bbuf + bwoff[cc]) =
          make_uint2(pk2(f[0 + cc], f[4 + cc]), pk2(f[8 + cc], f[12 + cc]));
  };
  auto COMPUTE = [&](int Aoff, const char* Bbuf) {
#pragma unroll
    for (int kk = 0; kk < 2; ++kk) {
      bf16x8 af[4], bf[4];
#pragma unroll
      for (int mi = 0; mi < 4; ++mi)
        af[mi] = *(const bf16x8*)(lds + Aoff + kk * 16384 + aoff[mi]);
#pragma unroll
      for (int ni = 0; ni < 4; ++ni)
        bf[ni] = *(const bf16x8*)(Bbuf + kk * 8192 + boff[ni]);
#pragma unroll
      for (int mi = 0; mi < 4; ++mi)
#pragma unroll
        for (int ni = 0; ni < 4; ++ni)
          acc[mi][ni] = __builtin_amdgcn_mfma_f32_16x16x32_bf16(af[mi], bf[ni], acc[mi][ni], 0, 0, 0);
    }
  };

  // prologue
  ISSUE_B(0); ISSUE_A(0, 0);
  WRITEB(Bb0);
  ISSUE_B(1); ISSUE_A(32768, 1);
  asm volatile("s_waitcnt vmcnt(8) lgkmcnt(0)" ::: "memory");
  __builtin_amdgcn_s_barrier();

  int aCur = 0, aNxt = 32768, aNx2 = 65536;
  for (int kt = 0; kt < NT; ++kt) {
    WRITEB((kt & 1) ? Bb0 : Bb1);
    const int tl = (kt + 2 < NT) ? kt + 2 : NT - 1;
    ISSUE_B(tl);
    ISSUE_A(aNx2, tl);
    COMPUTE(aCur, (kt & 1) ? Bb1 : Bb0);
    asm volatile("s_waitcnt vmcnt(8) lgkmcnt(0)" ::: "memory");
    __builtin_amdgcn_s_barrier();
    const int t = aCur; aCur = aNxt; aNxt = aNx2; aNx2 = t;
  }
  asm volatile("s_waitcnt vmcnt(0)" ::: "memory");
  __builtin_amdgcn_s_barrier();

  // ---- epilogue: relu, LDS transpose to H2-image (64KB @ lds+0) -------
  char* img = lds;
#pragma unroll
  for (int mi = 0; mi < 4; ++mi) {
#pragma unroll
    for (int ni = 0; ni < 4; ++ni) {
      const int colL = wc * 64 + ni * 16 + ln15;
      const int basei = (colL >> 6) * 32768 + ((colL >> 3) & 7) * 4096 + (colL & 7) * 2;
#pragma unroll
      for (int j = 0; j < 4; ++j) {
        const int rowL = wr * 64 + mi * 16 + l16 * 4 + j;
        float v = acc[mi][ni][j];
        v = v > 0.f ? v : 0.f;
        *(unsigned short*)(img + basei + rowL * 16) = f2bf(v);
      }
    }
  }
  __syncthreads();
  const char* src = img + tid * 128;
  char* dst = (char*)H2 + (size_t)e * 4194304 +
              (size_t)((n0 >> 6) + (tid >> 8)) * 65536 +
              (size_t)((tid >> 5) & 7) * 8192 +
              (size_t)(m0 + (tid & 31) * 8) * 16;
#pragma unroll
  for (int u = 0; u < 8; ++u)
    *(uint4*)(dst + u * 16) = *(const uint4*)(src + u * 16);
}

// ---------------- GEMM2: out[tok] = (H2[e] @ w2[e]) * gate -------------
#define G2_BX 2
#define G2_BY 8
#define G2_BZ 16
__global__ void __launch_bounds__(512, 2)
gemm2_kernel(const unsigned short* __restrict__ H2, const float* __restrict__ W2,
             const int* __restrict__ s2t, const float* __restrict__ gval,
             float* __restrict__ Out) {
  constexpr int NT = NF / 64;  // 64
  __shared__ __align__(16) char lds[131072];

  const int tid = threadIdx.x;
  const int lane = tid & 63, wid = tid >> 6;
  const int wr = wid >> 1, wc = wid & 1;
  const int ln15 = lane & 15, l16 = lane >> 4;

  const int flat = blockIdx.x + G2_BX * (blockIdx.y + G2_BY * blockIdx.z);
  const int xcd = flat & 7, jj = flat >> 3;      // jj 0..31
  const int e  = xcd * 2 + (jj >> 4);
  const int rr = jj & 15;
  const int by = rr >> 1, bx = rr & 1;
  const int m0 = bx * 256, n0 = by * 128;

  char* const Bb0 = lds + 98304;
  char* const Bb1 = lds + 98304 + 16384;

  const int rb = wid >> 1;
  const int kgw = (wid & 1) * 4;
  const int adst = kgw * 4096 + rb * 1024;
  const char* const Hex = (const char*)H2 + (size_t)e * 4194304 + (size_t)m0 * 16 +
                          (size_t)(rb * 64 + lane) * 16;

  const int c0 = (tid & 31) * 4;
  const int kq = tid >> 5;
  const float* const bsrc = W2 + (size_t)e * NF * DM + (size_t)(kq * 4) * DM + n0 + c0;
  const int kgb = kq >> 1, hb = kq & 1;
  int bwoff[4];
#pragma unroll
  for (int cc = 0; cc < 4; ++cc) bwoff[cc] = kgb * 2048 + pcol(c0 + cc) * 16 + hb * 8;

  int aoff[4], boff[4];
#pragma unroll
  for (int mi = 0; mi < 4; ++mi) aoff[mi] = l16 * 4096 + (wr * 64 + mi * 16 + ln15) * 16;
#pragma unroll
  for (int ni = 0; ni < 4; ++ni) boff[ni] = l16 * 2048 + pcol(wc * 64 + ni * 16 + ln15) * 16;

  f32x4 acc[4][4];
#pragma unroll
  for (int mi = 0; mi < 4; ++mi)
#pragma unroll
    for (int ni = 0; ni < 4; ++ni) acc[mi][ni] = f32x4{0.f, 0.f, 0.f, 0.f};

  float4 breg[4];

  auto ISSUE_B = [&](int kt) {
    const float* bp = bsrc + (size_t)kt * 64 * DM;
#pragma unroll
    for (int r = 0; r < 4; ++r) breg[r] = *(const float4*)(bp + (size_t)r * DM);
  };
  auto ISSUE_A = [&](int Aoff, int kt) {
#pragma unroll
    for (int j = 0; j < 4; ++j)
      gload_lds16(Hex + (size_t)kt * 65536 + (size_t)(kgw + j) * 8192,
                  lds + Aoff + adst + j * 4096);
  };
  auto WRITEB = [&](char* Bbuf) {
    const float* f = (const float*)breg;
#pragma unroll
    for (int cc = 0; cc < 4; ++cc)
      *(uint2*)(Bbuf + bwoff[cc]) =
          make_uint2(pk2(f[0 + cc], f[4 + cc]), pk2(f[8 + cc], f[12 + cc]));
  };
  auto COMPUTE = [&](int Aoff, const char* Bbuf) {
#pragma unroll
    for (int kk = 0; kk < 2; ++kk) {
      bf16x8 af[4], bf[4];
#pragma unroll
      for (int mi = 0; mi < 4; ++mi)
        af[mi] = *(const bf16x8*)(lds + Aoff + kk * 16384 + aoff[mi]);
#pragma unroll
      for (int ni = 0; ni < 4; ++ni)
        bf[ni] = *(const bf16x8*)(Bbuf + kk * 8192 + boff[ni]);
#pragma unroll
      for (int mi = 0; mi < 4; ++mi)
#pragma unroll
        for (int ni = 0; ni < 4; ++ni)
          acc[mi][ni] = __builtin_amdgcn_mfma_f32_16x16x32_bf16(af[mi], bf[ni], acc[mi][ni], 0, 0, 0);
    }
  };

  ISSUE_B(0); ISSUE_A(0, 0);
  WRITEB(Bb0);
  ISSUE_B(1); ISSUE_A(32768, 1);
  asm volatile("s_waitcnt vmcnt(8) lgkmcnt(0)" ::: "memory");
  __builtin_amdgcn_s_barrier();

  int aCur = 0, aNxt = 32768, aNx2 = 65536;
  for (int kt = 0; kt < NT; ++kt) {
    WRITEB((kt & 1) ? Bb0 : Bb1);
    const int tl = (kt + 2 < NT) ? kt + 2 : NT - 1;
    ISSUE_B(tl);
    ISSUE_A(aNx2, tl);
    COMPUTE(aCur, (kt & 1) ? Bb1 : Bb0);
    asm volatile("s_waitcnt vmcnt(8) lgkmcnt(0)" ::: "memory");
    __builtin_amdgcn_s_barrier();
    const int t = aCur; aCur = aNxt; aNxt = aNx2; aNx2 = t;
  }
  asm volatile("s_waitcnt vmcnt(0)" ::: "memory");

#pragma unroll
  for (int mi = 0; mi < 4; ++mi) {
#pragma unroll
    for (int ni = 0; ni < 4; ++ni) {
      const int col = n0 + wc * 64 + ni * 16 + ln15;
#pragma unroll
      for (int j = 0; j < 4; ++j) {
        const int row = m0 + wr * 64 + mi * 16 + l16 * 4 + j;
        const int tk = s2t[e * CAP + row];
        if (tk >= 0)
          Out[(size_t)tk * DM + col] = acc[mi][ni][j] * gval[tk];
      }
    }
  }
}

// ----------------------------- launcher --------------------------------
extern "C" void kernel_launch(void* const* d_in, const int* in_sizes, int n_in,
                              void* d_out, int out_size, void* d_ws, size_t ws_size,
                              hipStream_t stream) {
  (void)in_sizes; (void)n_in; (void)ws_size;
  const float* X  = (const float*)d_in[0];
  const float* Wg = (const float*)d_in[1];
  const float* W1 = (const float*)d_in[2];
  const float* W2 = (const float*)d_in[3];
  float* Out = (float*)d_out;

  char* ws = (char*)d_ws;
  int*   s2t  = (int*)ws;                            // 32 KB
  int*   idx  = (int*)(ws + 32768);
  float* gval = (float*)(ws + 65536);
  unsigned short* Xg = (unsigned short*)(ws + 98304);            // 16 MB blocked gathered
  unsigned short* H2 = (unsigned short*)(ws + 98304 + 16777216); // 64 MB blocked

  (void)hipMemsetAsync(d_out, 0, (size_t)out_size * sizeof(float), stream);
  gate_kernel<<<S_TOK / 16, 256, 0, stream>>>(X, Wg, idx, gval);
  scan_kernel<<<1, 1024, 0, stream>>>(idx, s2t);
  gather_kernel<<<512, 256, 0, stream>>>(X, s2t, Xg);
  gemm1_kernel<<<dim3(G1_BX, G1_BY, G1_BZ), 512, 0, stream>>>(Xg, W1, H2);
  gemm2_kernel<<<dim3(G2_BX, G2_BY, G2_BZ), 512, 0, stream>>>(H2, W2, s2t, gval, Out);
}

// Round 8
// 280.152 us; speedup vs baseline: 2.1680x; 1.0018x over previous
//
#include <hip/hip_runtime.h>
#include <cstdint>
#include <cstddef>

#define S_TOK 8192
#define DM    1024
#define NE    16
#define NF    4096
#define CAP   512

typedef __attribute__((ext_vector_type(8))) short bf16x8;
typedef __attribute__((ext_vector_type(4))) float f32x4;

__device__ __forceinline__ unsigned short f2bf(float f) {
  __bf16 b = (__bf16)f;
  return __builtin_bit_cast(unsigned short, b);
}
__device__ __forceinline__ unsigned pk2(float a, float b) {
  return (unsigned)f2bf(a) | ((unsigned)f2bf(b) << 16);
}
// bank-spread for the B [kg][col][16B] LDS layout
__device__ __forceinline__ int pcol(int c) { return c ^ ((c >> 3) & 7); }

__device__ __forceinline__ void gload_lds16(const void* g, void* l) {
  __builtin_amdgcn_global_load_lds(
      (const __attribute__((address_space(1))) void*)g,
      (__attribute__((address_space(3))) void*)l, 16, 0, 0);
}

// ---------------- fast zero of d_out (rocclr fill blit is ~150us!) -----
__global__ void __launch_bounds__(256)
zero_kernel(float4* __restrict__ Out, int n4) {
  const int stride = gridDim.x * 256;
  for (int i = blockIdx.x * 256 + threadIdx.x; i < n4; i += stride)
    Out[i] = float4{0.f, 0.f, 0.f, 0.f};
}

// ---------------- gating: logits fp32, softmax, argmax -----------------
__global__ void __launch_bounds__(256)
gate_kernel(const float* __restrict__ X, const float* __restrict__ Wg,
            int* __restrict__ idx, float* __restrict__ gval) {
  const int tid  = threadIdx.x;
  const int lane = tid & 63;
  const int wid  = tid >> 6;
  const int e = lane & 15, q = lane >> 4;
  const int t0 = blockIdx.x * 16 + wid * 4;
  const int mbase = q * 256;

  const float* xp0 = X + (size_t)(t0 + 0) * DM + mbase;
  const float* xp1 = X + (size_t)(t0 + 1) * DM + mbase;
  const float* xp2 = X + (size_t)(t0 + 2) * DM + mbase;
  const float* xp3 = X + (size_t)(t0 + 3) * DM + mbase;
  const float* wp  = Wg + (size_t)mbase * NE + e;

  float a0 = 0.f, a1 = 0.f, a2 = 0.f, a3 = 0.f;
#pragma unroll 4
  for (int i = 0; i < 64; ++i) {
    float4 x0 = *(const float4*)(xp0 + i * 4);
    float4 x1 = *(const float4*)(xp1 + i * 4);
    float4 x2 = *(const float4*)(xp2 + i * 4);
    float4 x3 = *(const float4*)(xp3 + i * 4);
    float w0 = wp[(i * 4 + 0) * NE];
    float w1 = wp[(i * 4 + 1) * NE];
    float w2 = wp[(i * 4 + 2) * NE];
    float w3 = wp[(i * 4 + 3) * NE];
    a0 = fmaf(x0.x, w0, fmaf(x0.y, w1, fmaf(x0.z, w2, fmaf(x0.w, w3, a0))));
    a1 = fmaf(x1.x, w0, fmaf(x1.y, w1, fmaf(x1.z, w2, fmaf(x1.w, w3, a1))));
    a2 = fmaf(x2.x, w0, fmaf(x2.y, w1, fmaf(x2.z, w2, fmaf(x2.w, w3, a2))));
    a3 = fmaf(x3.x, w0, fmaf(x3.y, w1, fmaf(x3.z, w2, fmaf(x3.w, w3, a3))));
  }
#pragma unroll
  for (int s = 16; s < 64; s <<= 1) {
    a0 += __shfl_xor(a0, s, 64);
    a1 += __shfl_xor(a1, s, 64);
    a2 += __shfl_xor(a2, s, 64);
    a3 += __shfl_xor(a3, s, 64);
  }
  float l = (q == 0) ? a0 : (q == 1) ? a1 : (q == 2) ? a2 : a3;
  float bv = l; int bi = e;
#pragma unroll
  for (int s = 1; s < 16; s <<= 1) {
    float ov = __shfl_xor(bv, s, 16);
    int   oi = __shfl_xor(bi, s, 16);
    if (ov > bv || (ov == bv && oi < bi)) { bv = ov; bi = oi; }
  }
  float p  = expf(l - bv);
  float sm = p;
#pragma unroll
  for (int s = 1; s < 16; s <<= 1) sm += __shfl_xor(sm, s, 16);
  if (e == 0) {
    idx[t0 + q]  = bi;
    gval[t0 + q] = 1.0f / sm;
  }
}

// ---------------- routing scan: capacity-limited slot assignment -------
__global__ void __launch_bounds__(1024)
scan_kernel(const int* __restrict__ idx, int* __restrict__ s2t) {
  const int tid = threadIdx.x;
#pragma unroll
  for (int k = 0; k < 8; ++k) s2t[tid + k * 1024] = -1;
  __shared__ int base[16];
  __shared__ int wavecnt[16][16];
  if (tid < 16) base[tid] = 0;
  __syncthreads();
  const int wid = tid >> 6, lane = tid & 63;
  const unsigned long long ltmask = (1ull << lane) - 1ull;
  for (int c = 0; c < 8; ++c) {
    const int t = c * 1024 + tid;
    const int e = idx[t];
    int rank = 0;
#pragma unroll
    for (int ee = 0; ee < 16; ++ee) {
      unsigned long long m = __ballot(e == ee);
      if (lane == 0) wavecnt[wid][ee] = __popcll(m);
      if (ee == e) rank = __popcll(m & ltmask);
    }
    __syncthreads();
    if (tid < 16) {
      int s = base[tid];
#pragma unroll
      for (int w = 0; w < 16; ++w) { int cc = wavecnt[w][tid]; wavecnt[w][tid] = s; s += cc; }
      base[tid] = s;
    }
    __syncthreads();
    const int loc = wavecnt[wid][e] + rank;
    if (loc < CAP) s2t[e * CAP + loc] = t;
    __syncthreads();
  }
}

// ---------------- gather + cvt: X fp32 rows -> blocked gathered bf16 ----
// Xg layout: [e][kt(16)][kg(8)][slot(512)][16B]; 1 MB/expert, 16 MB.
__global__ void __launch_bounds__(256)
gather_kernel(const float* __restrict__ X, const int* __restrict__ s2t,
              unsigned short* __restrict__ Xg) {
  const int tid = threadIdx.x;
  const int d  = tid & 127;           // 8 floats per thread
  const int sl = tid >> 7;            // 0..1
  const int s0 = blockIdx.x * 16;     // 16 slots per block
#pragma unroll 2
  for (int p = 0; p < 8; ++p) {
    const int s = s0 + p * 2 + sl;
    const int tok = s2t[s];
    uint4 w;
    if (tok >= 0) {
      const float* xp = X + (size_t)tok * DM + d * 8;
      float4 v0 = *(const float4*)xp;
      float4 v1 = *(const float4*)(xp + 4);
      w = make_uint4(pk2(v0.x, v0.y), pk2(v0.z, v0.w),
                     pk2(v1.x, v1.y), pk2(v1.z, v1.w));
    } else {
      w = make_uint4(0u, 0u, 0u, 0u);
    }
    char* dst = (char*)Xg + (size_t)(s >> 9) * 1048576 +
                (size_t)(d >> 3) * 65536 + (size_t)(d & 7) * 8192 +
                (size_t)(s & 511) * 16;
    *(uint4*)dst = w;
  }
}

// H2 layout: [e][kt(64)][kg(8)][row(512)][8 bf16]; per-expert 4 MB.

// =======================================================================
// GEMM skeleton: 256(M)x128(N) tile, BK=64, 512 thr (8 waves, 4Mx2N).
// A: triple-buffered LDS via global_load_lds (depth-2 prefetch, fully
//    contiguous blocked source for BOTH gemms).
// B: double-buffered LDS, reg-staged fp32->bf16 (loads 1 iter ahead).
// One raw s_barrier per iter with COUNTED s_waitcnt vmcnt(8).
// XCD co-location: xcd = flat&7 owns 2 experts.
// LDS: A 3x32KB @0, B 2x16KB @98304 = 128 KB.
// =======================================================================

// ---------------- GEMM1: H2[e] = relu(Xg[e] @ w1[e]) -------------------
#define G1_BX 2
#define G1_BY 32
#define G1_BZ 16
__global__ void __launch_bounds__(512, 2)
gemm1_kernel(const unsigned short* __restrict__ Xg, const float* __restrict__ W1,
             unsigned short* __restrict__ H2) {
  constexpr int NT = DM / 64;  // 16
  __shared__ __align__(16) char lds[131072];

  const int tid = threadIdx.x;
  const int lane = tid & 63, wid = tid >> 6;
  const int wr = wid >> 1, wc = wid & 1;
  const int ln15 = lane & 15, l16 = lane >> 4;

  const int flat = blockIdx.x + G1_BX * (blockIdx.y + G1_BY * blockIdx.z);
  const int xcd = flat & 7, jj = flat >> 3;      // jj 0..127
  const int e  = xcd * 2 + (jj >> 6);
  const int rr = jj & 63;
  const int by = rr >> 1, bx = rr & 1;
  const int m0 = bx * 256, n0 = by * 128;

  char* const Bb0 = lds + 98304;
  char* const Bb1 = lds + 98304 + 16384;

  // A: blocked gathered source; wave covers rows rb*64+lane, kg kgw..kgw+3
  const int rb = wid >> 1;
  const int kgw = (wid & 1) * 4;
  const int adst = kgw * 4096 + rb * 1024;
  const char* const Xge = (const char*)Xg + (size_t)e * 1048576 +
                          (size_t)(m0 + rb * 64 + lane) * 16;

  // B: cols c0..c0+3, k-rows 4*kq..4*kq+3
  const int c0 = (tid & 31) * 4;
  const int kq = tid >> 5;
  const float* const bsrc = W1 + (size_t)e * DM * NF + (size_t)(kq * 4) * NF + n0 + c0;
  const int kgb = kq >> 1, hb = kq & 1;
  int bwoff[4];
#pragma unroll
  for (int cc = 0; cc < 4; ++cc) bwoff[cc] = kgb * 2048 + pcol(c0 + cc) * 16 + hb * 8;

  int aoff[4], boff[4];
#pragma unroll
  for (int mi = 0; mi < 4; ++mi) aoff[mi] = l16 * 4096 + (wr * 64 + mi * 16 + ln15) * 16;
#pragma unroll
  for (int ni = 0; ni < 4; ++ni) boff[ni] = l16 * 2048 + pcol(wc * 64 + ni * 16 + ln15) * 16;

  f32x4 acc[4][4];
#pragma unroll
  for (int mi = 0; mi < 4; ++mi)
#pragma unroll
    for (int ni = 0; ni < 4; ++ni) acc[mi][ni] = f32x4{0.f, 0.f, 0.f, 0.f};

  float4 breg[4];

  auto ISSUE_B = [&](int kt) {
    const float* bp = bsrc + (size_t)kt * 64 * NF;
#pragma unroll
    for (int r = 0; r < 4; ++r) breg[r] = *(const float4*)(bp + (size_t)r * NF);
  };
  auto ISSUE_A = [&](int Aoff, int kt) {
#pragma unroll
    for (int j = 0; j < 4; ++j)
      gload_lds16(Xge + (size_t)kt * 65536 + (size_t)(kgw + j) * 8192,
                  lds + Aoff + adst + j * 4096);
  };
  auto WRITEB = [&](char* Bbuf) {
    const float* f = (const float*)breg;
#pragma unroll
    for (int cc = 0; cc < 4; ++cc)
      *(uint2*)(Bbuf + bwoff[cc]) =
          make_uint2(pk2(f[0 + cc], f[4 + cc]), pk2(f[8 + cc], f[12 + cc]));
  };
  auto COMPUTE = [&](int Aoff, const char* Bbuf) {
#pragma unroll
    for (int kk = 0; kk < 2; ++kk) {
      bf16x8 af[4], bf[4];
#pragma unroll
      for (int mi = 0; mi < 4; ++mi)
        af[mi] = *(const bf16x8*)(lds + Aoff + kk * 16384 + aoff[mi]);
#pragma unroll
      for (int ni = 0; ni < 4; ++ni)
        bf[ni] = *(const bf16x8*)(Bbuf + kk * 8192 + boff[ni]);
#pragma unroll
      for (int mi = 0; mi < 4; ++mi)
#pragma unroll
        for (int ni = 0; ni < 4; ++ni)
          acc[mi][ni] = __builtin_amdgcn_mfma_f32_16x16x32_bf16(af[mi], bf[ni], acc[mi][ni], 0, 0, 0);
    }
  };

  // prologue
  ISSUE_B(0); ISSUE_A(0, 0);
  WRITEB(Bb0);
  ISSUE_B(1); ISSUE_A(32768, 1);
  asm volatile("s_waitcnt vmcnt(8) lgkmcnt(0)" ::: "memory");
  __builtin_amdgcn_s_barrier();

  int aCur = 0, aNxt = 32768, aNx2 = 65536;
  for (int kt = 0; kt < NT; ++kt) {
    WRITEB((kt & 1) ? Bb0 : Bb1);
    const int tl = (kt + 2 < NT) ? kt + 2 : NT - 1;
    ISSUE_B(tl);
    ISSUE_A(aNx2, tl);
    COMPUTE(aCur, (kt & 1) ? Bb1 : Bb0);
    asm volatile("s_waitcnt vmcnt(8) lgkmcnt(0)" ::: "memory");
    __builtin_amdgcn_s_barrier();
    const int t = aCur; aCur = aNxt; aNxt = aNx2; aNx2 = t;
  }
  asm volatile("s_waitcnt vmcnt(0)" ::: "memory");
  __builtin_amdgcn_s_barrier();

  // ---- epilogue: relu, LDS transpose to H2-image (64KB @ lds+0) -------
  char* img = lds;
#pragma unroll
  for (int mi = 0; mi < 4; ++mi) {
#pragma unroll
    for (int ni = 0; ni < 4; ++ni) {
      const int colL = wc * 64 + ni * 16 + ln15;
      const int basei = (colL >> 6) * 32768 + ((colL >> 3) & 7) * 4096 + (colL & 7) * 2;
#pragma unroll
      for (int j = 0; j < 4; ++j) {
        const int rowL = wr * 64 + mi * 16 + l16 * 4 + j;
        float v = acc[mi][ni][j];
        v = v > 0.f ? v : 0.f;
        *(unsigned short*)(img + basei + rowL * 16) = f2bf(v);
      }
    }
  }
  __syncthreads();
  const char* src = img + tid * 128;
  char* dst = (char*)H2 + (size_t)e * 4194304 +
              (size_t)((n0 >> 6) + (tid >> 8)) * 65536 +
              (size_t)((tid >> 5) & 7) * 8192 +
              (size_t)(m0 + (tid & 31) * 8) * 16;
#pragma unroll
  for (int u = 0; u < 8; ++u)
    *(uint4*)(dst + u * 16) = *(const uint4*)(src + u * 16);
}

// ---------------- GEMM2: out[tok] = (H2[e] @ w2[e]) * gate -------------
#define G2_BX 2
#define G2_BY 8
#define G2_BZ 16
__global__ void __launch_bounds__(512, 2)
gemm2_kernel(const unsigned short* __restrict__ H2, const float* __restrict__ W2,
             const int* __restrict__ s2t, const float* __restrict__ gval,
             float* __restrict__ Out) {
  constexpr int NT = NF / 64;  // 64
  __shared__ __align__(16) char lds[131072];

  const int tid = threadIdx.x;
  const int lane = tid & 63, wid = tid >> 6;
  const int wr = wid >> 1, wc = wid & 1;
  const int ln15 = lane & 15, l16 = lane >> 4;

  const int flat = blockIdx.x + G2_BX * (blockIdx.y + G2_BY * blockIdx.z);
  const int xcd = flat & 7, jj = flat >> 3;      // jj 0..31
  const int e  = xcd * 2 + (jj >> 4);
  const int rr = jj & 15;
  const int by = rr >> 1, bx = rr & 1;
  const int m0 = bx * 256, n0 = by * 128;

  char* const Bb0 = lds + 98304;
  char* const Bb1 = lds + 98304 + 16384;

  const int rb = wid >> 1;
  const int kgw = (wid & 1) * 4;
  const int adst = kgw * 4096 + rb * 1024;
  const char* const Hex = (const char*)H2 + (size_t)e * 4194304 + (size_t)m0 * 16 +
                          (size_t)(rb * 64 + lane) * 16;

  const int c0 = (tid & 31) * 4;
  const int kq = tid >> 5;
  const float* const bsrc = W2 + (size_t)e * NF * DM + (size_t)(kq * 4) * DM + n0 + c0;
  const int kgb = kq >> 1, hb = kq & 1;
  int bwoff[4];
#pragma unroll
  for (int cc = 0; cc < 4; ++cc) bwoff[cc] = kgb * 2048 + pcol(c0 + cc) * 16 + hb * 8;

  int aoff[4], boff[4];
#pragma unroll
  for (int mi = 0; mi < 4; ++mi) aoff[mi] = l16 * 4096 + (wr * 64 + mi * 16 + ln15) * 16;
#pragma unroll
  for (int ni = 0; ni < 4; ++ni) boff[ni] = l16 * 2048 + pcol(wc * 64 + ni * 16 + ln15) * 16;

  f32x4 acc[4][4];
#pragma unroll
  for (int mi = 0; mi < 4; ++mi)
#pragma unroll
    for (int ni = 0; ni < 4; ++ni) acc[mi][ni] = f32x4{0.f, 0.f, 0.f, 0.f};

  float4 breg[4];

  auto ISSUE_B = [&](int kt) {
    const float* bp = bsrc + (size_t)kt * 64 * DM;
#pragma unroll
    for (int r = 0; r < 4; ++r) breg[r] = *(const float4*)(bp + (size_t)r * DM);
  };
  auto ISSUE_A = [&](int Aoff, int kt) {
#pragma unroll
    for (int j = 0; j < 4; ++j)
      gload_lds16(Hex + (size_t)kt * 65536 + (size_t)(kgw + j) * 8192,
                  lds + Aoff + adst + j * 4096);
  };
  auto WRITEB = [&](char* Bbuf) {
    const float* f = (const float*)breg;
#pragma unroll
    for (int cc = 0; cc < 4; ++cc)
      *(uint2*)(Bbuf + bwoff[cc]) =
          make_uint2(pk2(f[0 + cc], f[4 + cc]), pk2(f[8 + cc], f[12 + cc]));
  };
  auto COMPUTE = [&](int Aoff, const char* Bbuf) {
#pragma unroll
    for (int kk = 0; kk < 2; ++kk) {
      bf16x8 af[4], bf[4];
#pragma unroll
      for (int mi = 0; mi < 4; ++mi)
        af[mi] = *(const bf16x8*)(lds + Aoff + kk * 16384 + aoff[mi]);
#pragma unroll
      for (int ni = 0; ni < 4; ++ni)
        bf[ni] = *(const bf16x8*)(Bbuf + kk * 8192 + boff[ni]);
#pragma unroll
      for (int mi = 0; mi < 4; ++mi)
#pragma unroll
        for (int ni = 0; ni < 4; ++ni)
          acc[mi][ni] = __builtin_amdgcn_mfma_f32_16x16x32_bf16(af[mi], bf[ni], acc[mi][ni], 0, 0, 0);
    }
  };

  ISSUE_B(0); ISSUE_A(0, 0);
  WRITEB(Bb0);
  ISSUE_B(1); ISSUE_A(32768, 1);
  asm volatile("s_waitcnt vmcnt(8) lgkmcnt(0)" ::: "memory");
  __builtin_amdgcn_s_barrier();

  int aCur = 0, aNxt = 32768, aNx2 = 65536;
  for (int kt = 0; kt < NT; ++kt) {
    WRITEB((kt & 1) ? Bb0 : Bb1);
    const int tl = (kt + 2 < NT) ? kt + 2 : NT - 1;
    ISSUE_B(tl);
    ISSUE_A(aNx2, tl);
    COMPUTE(aCur, (kt & 1) ? Bb1 : Bb0);
    asm volatile("s_waitcnt vmcnt(8) lgkmcnt(0)" ::: "memory");
    __builtin_amdgcn_s_barrier();
    const int t = aCur; aCur = aNxt; aNxt = aNx2; aNx2 = t;
  }
  asm volatile("s_waitcnt vmcnt(0)" ::: "memory");

#pragma unroll
  for (int mi = 0; mi < 4; ++mi) {
#pragma unroll
    for (int ni = 0; ni < 4; ++ni) {
      const int col = n0 + wc * 64 + ni * 16 + ln15;
#pragma unroll
      for (int j = 0; j < 4; ++j) {
        const int row = m0 + wr * 64 + mi * 16 + l16 * 4 + j;
        const int tk = s2t[e * CAP + row];
        if (tk >= 0)
          Out[(size_t)tk * DM + col] = acc[mi][ni][j] * gval[tk];
      }
    }
  }
}

// ----------------------------- launcher --------------------------------
extern "C" void kernel_launch(void* const* d_in, const int* in_sizes, int n_in,
                              void* d_out, int out_size, void* d_ws, size_t ws_size,
                              hipStream_t stream) {
  (void)in_sizes; (void)n_in; (void)ws_size;
  const float* X  = (const float*)d_in[0];
  const float* Wg = (const float*)d_in[1];
  const float* W1 = (const float*)d_in[2];
  const float* W2 = (const float*)d_in[3];
  float* Out = (float*)d_out;

  char* ws = (char*)d_ws;
  int*   s2t  = (int*)ws;                            // 32 KB
  int*   idx  = (int*)(ws + 32768);
  float* gval = (float*)(ws + 65536);
  unsigned short* Xg = (unsigned short*)(ws + 98304);            // 16 MB blocked gathered
  unsigned short* H2 = (unsigned short*)(ws + 98304 + 16777216); // 64 MB blocked

  zero_kernel<<<2048, 256, 0, stream>>>((float4*)Out, out_size / 4);
  gate_kernel<<<S_TOK / 16, 256, 0, stream>>>(X, Wg, idx, gval);
  scan_kernel<<<1, 1024, 0, stream>>>(idx, s2t);
  gather_kernel<<<512, 256, 0, stream>>>(X, s2t, Xg);
  gemm1_kernel<<<dim3(G1_BX, G1_BY, G1_BZ), 512, 0, stream>>>(Xg, W1, H2);
  gemm2_kernel<<<dim3(G2_BX, G2_BY, G2_BZ), 512, 0, stream>>>(H2, W2, s2t, gval, Out);
}